// Round 13
// baseline (768.713 us; speedup 1.0000x reference)
//
#include <hip/hip_runtime.h>
#include <cmath>

#define NE_     200000
#define NR_     500
#define D_      128
#define TRIH_   256
#define TETH_   256
#define NTRI_   500000
#define NTET_   200000
#define B_      8192
#define EET_    1500000
#define ETT_    800000
#define EETT_   800000

#define CAP_V   2048
#define CAP_TP  8192
#define CAP_TRI 12288

#define ST_ET   64
#define ST_TT   32
#define ST_ETT  32

#define COARSEN 8
#define CHUNK   (256 * COARSEN)

#define NBC_V   ((NE_   + CHUNK - 1) / CHUNK)   // 98
#define NBC_TP  ((NTET_ + CHUNK - 1) / CHUNK)   // 98
#define NBC_TRI ((NTRI_ + CHUNK - 1) / CHUNK)   // 245
#define NBF_ET  ((EET_  + CHUNK - 1) / CHUNK)   // 733
#define NBF_TT  ((ETT_  + CHUNK - 1) / CHUNK)   // 391
#define NBF_ETT ((EETT_ + CHUNK - 1) / CHUNK)   // 391

#define NBLK_F  512
#define NBLK_B  512

#define WB_G2W1 0
#define WB_G2W2 32768
#define WB_G3W1 98304
#define WB_G3W2 163840
#define WB_TE   229376

// ctr: [0]=c_v [1]=c_tp [2]=c_tri [8]=barF [9]=barB  (zeroed via hipMemsetAsync)

typedef float f32x4 __attribute__((ext_vector_type(4)));
typedef short s16x8 __attribute__((ext_vector_type(8)));

__device__ __forceinline__ float gelu_exact(float v) {
    return 0.5f * v * (1.0f + erff(v * 0.70710678118654752f));
}

__device__ __forceinline__ unsigned short f2bf(float f) {
    unsigned int u = __float_as_uint(f);
    unsigned int r = (u + 0x7fffu + ((u >> 16) & 1u)) >> 16;
    return (unsigned short)r;
}

__device__ __forceinline__ float bf2f(unsigned int u) {
    return __uint_as_float(u << 16);
}

__device__ __forceinline__ int wave_rank_emit(bool pred, int* lcnt, int lane) {
    unsigned long long mask = __ballot(pred);
    int rank = __popcll(mask & ((1ull << lane) - 1ull));
    int total = __popcll(mask);
    int wb = 0;
    if (lane == 0 && total) wb = atomicAdd(lcnt, total);
    wb = __shfl(wb, 0, 64);
    return pred ? (wb + rank) : -1;
}

// device-wide spin barrier: agent-scope acq/rel (L2 wb/inv across XCDs).
// Requires all launched blocks co-resident (enforced via launch_bounds + LDS math).
__device__ __forceinline__ void gbar(int* bar, int target) {
    __syncthreads();
    if (threadIdx.x == 0) {
        __hip_atomic_fetch_add(bar, 1, __ATOMIC_ACQ_REL, __HIP_MEMORY_SCOPE_AGENT);
        while (__hip_atomic_load(bar, __ATOMIC_ACQUIRE, __HIP_MEMORY_SCOPE_AGENT) < target)
            __builtin_amdgcn_s_sleep(8);
    }
    __syncthreads();
}

// ---------------- building blocks (r11-validated bodies) ----------------

__device__ void do_compact(int* __restrict__ arr, int n, int* __restrict__ g, int cap,
                           int bid, int* lcnt, int* lbase) {
    if (threadIdx.x == 0) *lcnt = 0;
    __syncthreads();
    const int lane = threadIdx.x & 63;
    const int base = bid * CHUNK;
    int pos[COARSEN];
#pragma unroll
    for (int u = 0; u < COARSEN; ++u) {
        int e = base + u * 256 + threadIdx.x;
        bool pred = (e < n) && (arr[e] == -2);
        pos[u] = wave_rank_emit(pred, lcnt, lane);
    }
    __syncthreads();
    if (threadIdx.x == 0) *lbase = *lcnt ? atomicAdd(g, *lcnt) : 0;
    __syncthreads();
    const int b0 = *lbase;
#pragma unroll
    for (int u = 0; u < COARSEN; ++u) {
        if (pos[u] >= 0) {
            int e = base + u * 256 + threadIdx.x;
            int idx = b0 + pos[u];
            arr[e] = (idx < cap) ? idx : -1;
        }
    }
}

__device__ void do_filter(const int* __restrict__ e0, const int* __restrict__ e1,
                          const int* __restrict__ map0, const int* __restrict__ map1,
                          int n, int* __restrict__ deg, int* __restrict__ bkt,
                          int stride, int bid) {
#pragma unroll
    for (int u = 0; u < COARSEN; ++u) {
        int e = bid * CHUNK + u * 256 + threadIdx.x;
        if (e < n) {
            int m1 = map1[e1[e]];
            if (m1 >= 0) {
                int src = map0 ? map0[e0[e]] : e0[e];
                if (src >= 0) {
                    int slot = atomicAdd(&deg[m1], 1);
                    if (slot < stride) bkt[m1 * stride + slot] = src;
                }
            }
        }
    }
}

// ---------------- K2: mega front-end (6 phases, 5 barriers) ----------------

__launch_bounds__(256, 2)
__global__ void mega_front(const int* __restrict__ triples, const int* __restrict__ et,
                           const int* __restrict__ tt, const int* __restrict__ ett,
                           const float* __restrict__ w1, const float* __restrict__ w2,
                           const float* __restrict__ w3, const float* __restrict__ w4,
                           const float* __restrict__ w5, unsigned short* __restrict__ wb,
                           int* __restrict__ id_v, int* __restrict__ id_tp,
                           int* __restrict__ id_tri, int* __restrict__ ctr,
                           int* __restrict__ deg_tri, int* __restrict__ deg_tp,
                           int* __restrict__ deg_v, int* __restrict__ b_et,
                           int* __restrict__ b_tt, int* __restrict__ b_ett) {
    __shared__ int lcnt, lbase;
    int* bar = &ctr[8];
    const int tid0 = blockIdx.x * 256 + threadIdx.x;
    const int gsz = NBLK_F * 256;

    // P0: init ids + weight cvt + zero degs (ctr/bar zeroed by host memset)
    for (int x = tid0; x < NE_; x += gsz) id_v[x] = -1;
    for (int x = tid0; x < NTET_; x += gsz) id_tp[x] = -1;
    for (int x = tid0; x < NTRI_; x += gsz) id_tri[x] = -1;
    for (int x = tid0; x < 262144; x += gsz) {
        float f;
        if (x < 32768)       f = w1[x];
        else if (x < 98304)  f = w2[x - 32768];
        else if (x < 163840) f = w3[x - 98304];
        else if (x < 229376) f = w4[x - 163840];
        else                 f = w5[x - 229376];
        wb[x] = f2bf(f);
    }
    for (int x = tid0; x < CAP_TRI; x += gsz) deg_tri[x] = 0;
    for (int x = tid0; x < CAP_TP; x += gsz) deg_tp[x] = 0;
    for (int x = tid0; x < CAP_V; x += gsz) deg_v[x] = 0;
    gbar(bar, 1 * NBLK_F);

    // P1: mark_v
    for (int b = tid0; b < B_; b += gsz) {
        id_v[triples[3 * b + 0]] = -2;
        id_v[triples[3 * b + 2]] = -2;
    }
    gbar(bar, 2 * NBLK_F);

    // P2: mark_tp
    for (int e = tid0; e < EETT_; e += gsz)
        if (id_v[ett[e]] != -1) id_tp[ett[EETT_ + e]] = -2;
    gbar(bar, 3 * NBLK_F);

    // P3: compact_v || compact_tp || mark_tri (race on id_tp benign: -2 and id>=0 both != -1)
    if (blockIdx.x < NBC_V) {
        do_compact(id_v, NE_, &ctr[0], CAP_V, blockIdx.x, &lcnt, &lbase);
    } else if (blockIdx.x < NBC_V + NBC_TP) {
        do_compact(id_tp, NTET_, &ctr[1], CAP_TP, blockIdx.x - NBC_V, &lcnt, &lbase);
    } else {
        int i = (blockIdx.x - NBC_V - NBC_TP) * 256 + threadIdx.x;
        int st = (NBLK_F - NBC_V - NBC_TP) * 256;
        for (int e = i; e < ETT_; e += st)
            if (id_tp[tt[ETT_ + e]] != -1) id_tri[tt[e]] = -2;
    }
    gbar(bar, 4 * NBLK_F);

    // P4: compact_tri || filter_ett
    if (blockIdx.x < NBC_TRI) {
        do_compact(id_tri, NTRI_, &ctr[2], CAP_TRI, blockIdx.x, &lcnt, &lbase);
    } else {
        for (int ch = blockIdx.x - NBC_TRI; ch < NBF_ETT; ch += NBLK_F - NBC_TRI)
            do_filter(ett + EETT_, ett, id_tp, id_v, EETT_, deg_v, b_ett, ST_ETT, ch);
    }
    gbar(bar, 5 * NBLK_F);

    // P5: filter_et || filter_tt
    if (blockIdx.x < 352) {
        for (int ch = blockIdx.x; ch < NBF_ET; ch += 352)
            do_filter(et, et + EET_, nullptr, id_tri, EET_, deg_tri, b_et, ST_ET, ch);
    } else {
        for (int ch = blockIdx.x - 352; ch < NBF_TT; ch += NBLK_F - 352)
            do_filter(tt, tt + ETT_, id_tri, id_tp, ETT_, deg_tp, b_tt, ST_TT, ch);
    }
}

// ---------------- K3: gather-mean entity->triangle (wide grid, latency-bound) ----------------

__global__ void k_gather_tri(const int* __restrict__ ctr, const int* __restrict__ deg,
                             const int* __restrict__ bkt, const float* __restrict__ emb,
                             unsigned* __restrict__ outb) {
    const int c = min(ctr[2], CAP_TRI);
    const int lane = threadIdx.x & 63;
    int row = (blockIdx.x * blockDim.x + threadIdx.x) >> 6;
    const int nw = (gridDim.x * blockDim.x) >> 6;
    for (; row < c; row += nw) {
        int d = deg[row];
        int m = min(d, ST_ET);
        float ax = 0.f, ay = 0.f;
        for (int k = 0; k < m; ++k) {
            unsigned si = (unsigned)bkt[row * ST_ET + k];
            if (si < NE_) {
                float2 v = ((const float2*)(emb + (size_t)si * 128))[lane];
                ax += v.x; ay += v.y;
            }
        }
        float inv = (d > 0) ? 1.f / (float)d : 0.f;
        outb[(size_t)row * 64 + lane] =
            (unsigned)f2bf(ax * inv) | ((unsigned)f2bf(ay * inv) << 16);
    }
}

// ---------------- MFMA helpers (r10/r11-validated) ----------------

template<int KU>
__device__ __forceinline__ f32x4 tile_mma(const uint4* pa, int sa, const uint4* pb, int sb,
                                          int fo, f32x4 acc) {
#pragma unroll
    for (int kk = 0; kk < KU / 4; ++kk) {
        s16x8 a = *(const s16x8*)&pa[(kk * 4 + fo) ^ sa];
        s16x8 b = *(const s16x8*)&pb[(kk * 4 + fo) ^ sb];
        acc = __builtin_amdgcn_mfma_f32_16x16x32_bf16(a, b, acc, 0, 0, 0);
    }
    return acc;
}

template<int K, int ACT, bool OBF>
__device__ __forceinline__ void gemm_unit(int bx, int by, int c,
                                          const unsigned short* __restrict__ A,
                                          const unsigned short* __restrict__ Wb,
                                          const float* __restrict__ bias,
                                          void* __restrict__ Cv, int N,
                                          uint4* xs, uint4* ws) {
    constexpr int KU = K / 8;
    const int row0 = bx * 32;
    if (row0 < c) {
        const int tid = threadIdx.x;
        const int gc0 = by * 64;
#pragma unroll
        for (int it = 0; it < KU / 8; ++it) {
            int u = tid + it * 256;
            int r = u / KU, ku = u % KU;
            xs[r * KU + (ku ^ (r & 7))] = *(const uint4*)&A[(size_t)(row0 + r) * K + ku * 8];
        }
#pragma unroll
        for (int it = 0; it < KU / 4; ++it) {
            int u = tid + it * 256;
            int r = u / KU, ku = u % KU;
            ws[r * KU + (ku ^ (r & 7))] = *(const uint4*)&Wb[(size_t)(gc0 + r) * K + ku * 8];
        }
        __syncthreads();
        const int w = tid >> 6, l = tid & 63;
        const int wr = (w >> 1) * 16, wc0 = (w & 1) * 32;
        const int fr = l & 15, fo = l >> 4;
        const int ra = wr + fr, rb0 = wc0 + fr, rb1 = wc0 + 16 + fr;
        f32x4 z = {0.f, 0.f, 0.f, 0.f};
        f32x4 acc0 = tile_mma<KU>(xs + ra * KU, ra & 7, ws + rb0 * KU, rb0 & 7, fo, z);
        f32x4 acc1 = tile_mma<KU>(xs + ra * KU, ra & 7, ws + rb1 * KU, rb1 & 7, fo, z);
        const int col0 = gc0 + wc0 + fr, col1 = col0 + 16;
        const float bb0 = bias[col0], bb1 = bias[col1];
#pragma unroll
        for (int j = 0; j < 4; ++j) {
            int grow = row0 + wr + fo * 4 + j;
            if (grow < c) {
                float v0 = acc0[j] + bb0;
                float v1 = acc1[j] + bb1;
                if (ACT == 1) { v0 = gelu_exact(v0); v1 = gelu_exact(v1); }
                if (OBF) {
                    ((unsigned short*)Cv)[(size_t)grow * N + col0] = f2bf(v0);
                    ((unsigned short*)Cv)[(size_t)grow * N + col1] = f2bf(v1);
                } else {
                    ((float*)Cv)[(size_t)grow * N + col0] = v0;
                    ((float*)Cv)[(size_t)grow * N + col1] = v1;
                }
            }
        }
        __syncthreads();
    }
}

__device__ __forceinline__ void tet1_unit(int bx, int by, int c,
                                          const int* __restrict__ deg, const int* __restrict__ bkt,
                                          const unsigned short* __restrict__ tri_c,
                                          const unsigned short* __restrict__ Wb,
                                          const float* __restrict__ bias,
                                          unsigned short* __restrict__ h_tet,
                                          uint4* xs, uint4* ws) {
    constexpr int KU = 32;
    const int row0 = bx * 32;
    if (row0 < c) {
        const int tid = threadIdx.x, lane = tid & 63, wv = tid >> 6;
        const int gc0 = by * 64;
        for (int rr = wv * 8; rr < wv * 8 + 8; ++rr) {
            int row = row0 + rr;
            float a0 = 0.f, a1 = 0.f, a2 = 0.f, a3 = 0.f;
            int d = 0;
            if (row < c) {
                d = deg[row];
                int m = min(d, ST_TT);
                for (int k = 0; k < m; ++k) {
                    unsigned si = (unsigned)bkt[row * ST_TT + k];
                    if (si < CAP_TRI) {
                        uint2 p = ((const uint2*)(tri_c + (size_t)si * 256))[lane];
                        a0 += bf2f(p.x & 0xffffu); a1 += bf2f(p.x >> 16);
                        a2 += bf2f(p.y & 0xffffu); a3 += bf2f(p.y >> 16);
                    }
                }
            }
            float inv = (d > 0) ? 1.f / (float)d : 0.f;
            uint2 o;
            o.x = (unsigned)f2bf(a0 * inv) | ((unsigned)f2bf(a1 * inv) << 16);
            o.y = (unsigned)f2bf(a2 * inv) | ((unsigned)f2bf(a3 * inv) << 16);
            int col0 = lane * 4;
            int ku = col0 >> 3, off = col0 & 7;
            *(uint2*)((unsigned short*)&xs[rr * KU + (ku ^ (rr & 7))] + off) = o;
        }
#pragma unroll
        for (int it = 0; it < KU / 4; ++it) {
            int u = tid + it * 256;
            int r = u / KU, ku = u % KU;
            ws[r * KU + (ku ^ (r & 7))] = *(const uint4*)&Wb[(size_t)(gc0 + r) * 256 + ku * 8];
        }
        __syncthreads();
        const int w = tid >> 6;
        const int wr = (w >> 1) * 16, wc0 = (w & 1) * 32;
        const int fr = lane & 15, fo = lane >> 4;
        const int ra = wr + fr, rb0 = wc0 + fr, rb1 = wc0 + 16 + fr;
        f32x4 z = {0.f, 0.f, 0.f, 0.f};
        f32x4 acc0 = tile_mma<KU>(xs + ra * KU, ra & 7, ws + rb0 * KU, rb0 & 7, fo, z);
        f32x4 acc1 = tile_mma<KU>(xs + ra * KU, ra & 7, ws + rb1 * KU, rb1 & 7, fo, z);
        const int col0 = gc0 + wc0 + fr, col1 = col0 + 16;
        const float bb0 = bias[col0], bb1 = bias[col1];
#pragma unroll
        for (int j = 0; j < 4; ++j) {
            int grow = row0 + wr + fo * 4 + j;
            if (grow < c) {
                h_tet[(size_t)grow * 256 + col0] = f2bf(gelu_exact(acc0[j] + bb0));
                h_tet[(size_t)grow * 256 + col1] = f2bf(gelu_exact(acc1[j] + bb1));
            }
        }
        __syncthreads();
    }
}

// ---------------- K4: mega back-end (6 phases, 5 barriers) ----------------

__launch_bounds__(256, 2)
__global__ void mega_back(const int* __restrict__ ctr, const unsigned short* __restrict__ wb,
                          const unsigned short* __restrict__ tri_agg,
                          unsigned short* __restrict__ h_tri, unsigned short* __restrict__ tri_c,
                          const int* __restrict__ deg_tp, const int* __restrict__ b_tt,
                          unsigned short* __restrict__ h_tet, unsigned short* __restrict__ y_tet,
                          float* __restrict__ tet_proj,
                          const int* __restrict__ deg_v, const int* __restrict__ b_ett,
                          const int* __restrict__ id_v,
                          const float* __restrict__ g2b1, const float* __restrict__ g2b2,
                          const float* __restrict__ g3b1, const float* __restrict__ g3b2,
                          const float* __restrict__ teb,
                          const float* __restrict__ emb, const float* __restrict__ rel,
                          const float* __restrict__ lnw, const float* __restrict__ lnb,
                          const float* __restrict__ alpha, const float* __restrict__ gamma,
                          const int* __restrict__ triples, float* __restrict__ out,
                          int* __restrict__ barp) {
    __shared__ __align__(16) uint4 xs[32 * 32];   // 16 KB
    __shared__ __align__(16) uint4 ws[64 * 32];   // 32 KB
    const int c_tri = min(ctr[2], CAP_TRI);
    const int c_tp = min(ctr[1], CAP_TP);

    // P0: tri L1 (K=128, gelu) -> h_tri ; units 384x4
    for (int u = blockIdx.x; u < (CAP_TRI / 32) * 4; u += NBLK_B)
        gemm_unit<128, 1, true>(u % (CAP_TRI / 32), u / (CAP_TRI / 32), c_tri,
                                tri_agg, wb + WB_G2W1, g2b1, h_tri, TRIH_, xs, ws);
    gbar(barp, 1 * NBLK_B);

    // P1: tri L2 (K=256) -> tri_c
    for (int u = blockIdx.x; u < (CAP_TRI / 32) * 4; u += NBLK_B)
        gemm_unit<256, 0, true>(u % (CAP_TRI / 32), u / (CAP_TRI / 32), c_tri,
                                h_tri, wb + WB_G2W2, g2b2, tri_c, TRIH_, xs, ws);
    gbar(barp, 2 * NBLK_B);

    // P2: tet gather + L1 -> h_tet ; units 256x4
    for (int u = blockIdx.x; u < (CAP_TP / 32) * 4; u += NBLK_B)
        tet1_unit(u % (CAP_TP / 32), u / (CAP_TP / 32), c_tp,
                  deg_tp, b_tt, tri_c, wb + WB_G3W1, g3b1, h_tet, xs, ws);
    gbar(barp, 3 * NBLK_B);

    // P3: tet L2 -> y_tet
    for (int u = blockIdx.x; u < (CAP_TP / 32) * 4; u += NBLK_B)
        gemm_unit<256, 0, true>(u % (CAP_TP / 32), u / (CAP_TP / 32), c_tp,
                                h_tet, wb + WB_G3W2, g3b2, y_tet, TETH_, xs, ws);
    gbar(barp, 4 * NBLK_B);

    // P4: proj -> tet_proj (f32) ; units 256x2
    for (int u = blockIdx.x; u < (CAP_TP / 32) * 2; u += NBLK_B)
        gemm_unit<256, 0, false>(u % (CAP_TP / 32), u / (CAP_TP / 32), c_tp,
                                 y_tet, wb + WB_TE, teb, tet_proj, D_, xs, ws);
    gbar(barp, 5 * NBLK_B);

    // P5: final (v-gather + mean + LN + fusion + TransE), wave per triple
    {
        const int lane = threadIdx.x & 63;
        int gw = blockIdx.x * 4 + (threadIdx.x >> 6);
        const int nw = NBLK_B * 4;
        float a0 = alpha[0], a1 = alpha[1];
        float m = fmaxf(a0, a1);
        float e0 = expf(a0 - m), e1 = expf(a1 - m);
        float w0 = e0 / (e0 + e1), w1 = e1 / (e0 + e1);
        for (int b = gw; b < B_; b += nw) {
            int h = triples[b * 3 + 0];
            int r = triples[b * 3 + 1];
            int t = triples[b * 3 + 2];
            int jh = id_v[h]; jh = (jh >= 0 && jh < CAP_V) ? jh : 0;
            int jt = id_v[t]; jt = (jt >= 0 && jt < CAP_V) ? jt : 0;
            float2 xh = make_float2(0.f, 0.f), xt = make_float2(0.f, 0.f);
            {
                int d = deg_v[jh], mm = min(d, ST_ETT);
                for (int k = 0; k < mm; ++k) {
                    unsigned si = (unsigned)b_ett[jh * ST_ETT + k];
                    if (si < CAP_TP) {
                        float2 v = ((const float2*)(tet_proj + (size_t)si * 128))[lane];
                        xh.x += v.x; xh.y += v.y;
                    }
                }
                float inv = (d > 0) ? 1.f / (float)d : 0.f;
                xh.x *= inv; xh.y *= inv;
            }
            {
                int d = deg_v[jt], mm = min(d, ST_ETT);
                for (int k = 0; k < mm; ++k) {
                    unsigned si = (unsigned)b_ett[jt * ST_ETT + k];
                    if (si < CAP_TP) {
                        float2 v = ((const float2*)(tet_proj + (size_t)si * 128))[lane];
                        xt.x += v.x; xt.y += v.y;
                    }
                }
                float inv = (d > 0) ? 1.f / (float)d : 0.f;
                xt.x *= inv; xt.y *= inv;
            }
            float sh = xh.x + xh.y, st = xt.x + xt.y;
#pragma unroll
            for (int o = 32; o >= 1; o >>= 1) { sh += __shfl_xor(sh, o, 64); st += __shfl_xor(st, o, 64); }
            float muh = sh * (1.f / 128.f), mut = st * (1.f / 128.f);
            float2 dh = make_float2(xh.x - muh, xh.y - muh);
            float2 dt = make_float2(xt.x - mut, xt.y - mut);
            float vh_ = dh.x * dh.x + dh.y * dh.y, vt_ = dt.x * dt.x + dt.y * dt.y;
#pragma unroll
            for (int o = 32; o >= 1; o >>= 1) { vh_ += __shfl_xor(vh_, o, 64); vt_ += __shfl_xor(vt_, o, 64); }
            float rsh = rsqrtf(vh_ * (1.f / 128.f) + 1e-5f);
            float rst = rsqrtf(vt_ * (1.f / 128.f) + 1e-5f);
            float2 lw = ((const float2*)lnw)[lane];
            float2 lb = ((const float2*)lnb)[lane];
            float2 lnh = make_float2(dh.x * rsh * lw.x + lb.x, dh.y * rsh * lw.y + lb.y);
            float2 lnt = make_float2(dt.x * rst * lw.x + lb.x, dt.y * rst * lw.y + lb.y);
            float2 eh = ((const float2*)emb)[(size_t)h * 64 + lane];
            float2 etv = ((const float2*)emb)[(size_t)t * 64 + lane];
            float2 rr = ((const float2*)rel)[(size_t)r * 64 + lane];
            float dx = (w0 * eh.x + w1 * lnh.x) + rr.x - (w0 * etv.x + w1 * lnt.x);
            float dy = (w0 * eh.y + w1 * lnh.y) + rr.y - (w0 * etv.y + w1 * lnt.y);
            float ss = dx * dx + dy * dy;
#pragma unroll
            for (int o = 32; o >= 1; o >>= 1) ss += __shfl_xor(ss, o, 64);
            if (lane == 0) out[b] = gamma[0] - sqrtf(ss);
        }
    }
}

// ---------------- host launcher ----------------

extern "C" void kernel_launch(void* const* d_in, const int* in_sizes, int n_in,
                              void* d_out, int out_size, void* d_ws, size_t ws_size,
                              hipStream_t stream) {
    const float* entity_emb = (const float*)d_in[0];
    const float* relation_emb = (const float*)d_in[1];
    const float* g2_w1 = (const float*)d_in[2];
    const float* g2_b1 = (const float*)d_in[3];
    const float* g2_w2 = (const float*)d_in[4];
    const float* g2_b2 = (const float*)d_in[5];
    const float* g3_w1 = (const float*)d_in[6];
    const float* g3_b1 = (const float*)d_in[7];
    const float* g3_w2 = (const float*)d_in[8];
    const float* g3_b2 = (const float*)d_in[9];
    const float* te_w = (const float*)d_in[10];
    const float* te_b = (const float*)d_in[11];
    const float* ln_w = (const float*)d_in[12];
    const float* ln_b = (const float*)d_in[13];
    const float* alpha = (const float*)d_in[14];
    const float* gamma = (const float*)d_in[15];
    const int* triples = (const int*)d_in[16];
    const int* et = (const int*)d_in[17];
    const int* tt = (const int*)d_in[18];
    const int* ett = (const int*)d_in[19];
    float* out = (float*)d_out;

    char* base = (char*)d_ws;
    size_t off = 0;
    auto take = [&](size_t bytes) -> void* {
        void* p = base + off;
        off = (off + bytes + 255) & ~(size_t)255;
        return p;
    };
    int* id_v = (int*)take((size_t)NE_ * 4);
    int* id_tp = (int*)take((size_t)NTET_ * 4);
    int* id_tri = (int*)take((size_t)NTRI_ * 4);
    int* ctr = (int*)take(64);
    int* deg_tri = (int*)take((size_t)CAP_TRI * 4);
    int* deg_tp = (int*)take((size_t)CAP_TP * 4);
    int* deg_v = (int*)take((size_t)CAP_V * 4);
    int* b_et = (int*)take((size_t)CAP_TRI * ST_ET * 4);
    int* b_tt = (int*)take((size_t)CAP_TP * ST_TT * 4);
    int* b_ett = (int*)take((size_t)CAP_V * ST_ETT * 4);
    unsigned short* wb = (unsigned short*)take((size_t)262144 * 2);
    unsigned short* tri_agg = (unsigned short*)take((size_t)CAP_TRI * D_ * 2);
    unsigned short* h_tri = (unsigned short*)take((size_t)CAP_TRI * TRIH_ * 2);
    unsigned short* tri_c = (unsigned short*)take((size_t)CAP_TRI * TRIH_ * 2);
    unsigned short* h_tet = (unsigned short*)take((size_t)CAP_TP * TETH_ * 2);
    unsigned short* y_tet = (unsigned short*)take((size_t)CAP_TP * TETH_ * 2);
    float* tet_proj = (float*)take((size_t)CAP_TP * D_ * 4);
    if (off > ws_size) return;  // workspace too small -> visible validation failure

    hipMemsetAsync(ctr, 0, 64, stream);  // counters + both spin-barrier words

    mega_front<<<NBLK_F, 256, 0, stream>>>(triples, et, tt, ett,
                                           g2_w1, g2_w2, g3_w1, g3_w2, te_w, wb,
                                           id_v, id_tp, id_tri, ctr,
                                           deg_tri, deg_tp, deg_v, b_et, b_tt, b_ett);
    k_gather_tri<<<2048, 256, 0, stream>>>(ctr, deg_tri, b_et, entity_emb, (unsigned*)tri_agg);
    mega_back<<<NBLK_B, 256, 0, stream>>>(ctr, wb, tri_agg, h_tri, tri_c,
                                          deg_tp, b_tt, h_tet, y_tet, tet_proj,
                                          deg_v, b_ett, id_v,
                                          g2_b1, g2_b2, g3_b1, g3_b2, te_b,
                                          entity_emb, relation_emb, ln_w, ln_b,
                                          alpha, gamma, triples, out, &ctr[9]);
}

// Round 14
// 759.363 us; speedup vs baseline: 1.0123x; 1.0123x over previous
//
#include <hip/hip_runtime.h>
#include <cmath>

#define NE_     200000
#define NR_     500
#define D_      128
#define TRIH_   256
#define TETH_   256
#define NTRI_   500000
#define NTET_   200000
#define B_      8192
#define EET_    1500000
#define ETT_    800000
#define EETT_   800000

#define CAP_V   2048
#define CAP_TP  8192
#define CAP_TRI 12288

#define ST_ET   64
#define ST_TT   32
#define ST_ETT  32

#define COARSEN 8
#define CHUNK   (256 * COARSEN)

#define NBC_V   ((NE_   + CHUNK - 1) / CHUNK)   // 98
#define NBC_TP  ((NTET_ + CHUNK - 1) / CHUNK)   // 98
#define NBC_TRI ((NTRI_ + CHUNK - 1) / CHUNK)   // 245
#define NBF_ET  ((EET_  + CHUNK - 1) / CHUNK)   // 733
#define NBF_TT  ((ETT_  + CHUNK - 1) / CHUNK)   // 391
#define NBF_ETT ((EETT_ + CHUNK - 1) / CHUNK)   // 391

#define NBLK_F  512
#define NBLK_B  512

#define WB_G2W1 0
#define WB_G2W2 32768
#define WB_G3W1 98304
#define WB_G3W2 163840
#define WB_TE   229376

// ctr: [0]=c_v [1]=c_tp [2]=c_tri [8]=barF [9]=barB  (zeroed via hipMemsetAsync)

typedef float f32x4 __attribute__((ext_vector_type(4)));
typedef short s16x8 __attribute__((ext_vector_type(8)));

__device__ __forceinline__ float gelu_exact(float v) {
    return 0.5f * v * (1.0f + erff(v * 0.70710678118654752f));
}

__device__ __forceinline__ unsigned short f2bf(float f) {
    unsigned int u = __float_as_uint(f);
    unsigned int r = (u + 0x7fffu + ((u >> 16) & 1u)) >> 16;
    return (unsigned short)r;
}

__device__ __forceinline__ float bf2f(unsigned int u) {
    return __uint_as_float(u << 16);
}

__device__ __forceinline__ int wave_rank_emit(bool pred, int* lcnt, int lane) {
    unsigned long long mask = __ballot(pred);
    int rank = __popcll(mask & ((1ull << lane) - 1ull));
    int total = __popcll(mask);
    int wb = 0;
    if (lane == 0 && total) wb = atomicAdd(lcnt, total);
    wb = __shfl(wb, 0, 64);
    return pred ? (wb + rank) : -1;
}

// device-wide spin barrier: agent-scope acq/rel (L2 wb/inv across XCDs).
// Requires all launched blocks co-resident (enforced via launch_bounds + LDS math).
__device__ __forceinline__ void gbar(int* bar, int target) {
    __syncthreads();
    if (threadIdx.x == 0) {
        __hip_atomic_fetch_add(bar, 1, __ATOMIC_ACQ_REL, __HIP_MEMORY_SCOPE_AGENT);
        while (__hip_atomic_load(bar, __ATOMIC_ACQUIRE, __HIP_MEMORY_SCOPE_AGENT) < target)
            __builtin_amdgcn_s_sleep(8);
    }
    __syncthreads();
}

// ---------------- building blocks (r11-validated bodies) ----------------

__device__ void do_compact(int* __restrict__ arr, int n, int* __restrict__ g, int cap,
                           int bid, int* lcnt, int* lbase) {
    if (threadIdx.x == 0) *lcnt = 0;
    __syncthreads();
    const int lane = threadIdx.x & 63;
    const int base = bid * CHUNK;
    int pos[COARSEN];
#pragma unroll
    for (int u = 0; u < COARSEN; ++u) {
        int e = base + u * 256 + threadIdx.x;
        bool pred = (e < n) && (arr[e] == -2);
        pos[u] = wave_rank_emit(pred, lcnt, lane);
    }
    __syncthreads();
    if (threadIdx.x == 0) *lbase = *lcnt ? atomicAdd(g, *lcnt) : 0;
    __syncthreads();
    const int b0 = *lbase;
#pragma unroll
    for (int u = 0; u < COARSEN; ++u) {
        if (pos[u] >= 0) {
            int e = base + u * 256 + threadIdx.x;
            int idx = b0 + pos[u];
            arr[e] = (idx < cap) ? idx : -1;
        }
    }
}

__device__ void do_filter(const int* __restrict__ e0, const int* __restrict__ e1,
                          const int* __restrict__ map0, const int* __restrict__ map1,
                          int n, int* __restrict__ deg, int* __restrict__ bkt,
                          int stride, int bid) {
#pragma unroll
    for (int u = 0; u < COARSEN; ++u) {
        int e = bid * CHUNK + u * 256 + threadIdx.x;
        if (e < n) {
            int m1 = map1[e1[e]];
            if (m1 >= 0) {
                int src = map0 ? map0[e0[e]] : e0[e];
                if (src >= 0) {
                    int slot = atomicAdd(&deg[m1], 1);
                    if (slot < stride) bkt[m1 * stride + slot] = src;
                }
            }
        }
    }
}

// ---------------- K2: mega front-end (6 phases, 5 barriers) ----------------

__launch_bounds__(256, 2)
__global__ void mega_front(const int* __restrict__ triples, const int* __restrict__ et,
                           const int* __restrict__ tt, const int* __restrict__ ett,
                           const float* __restrict__ w1, const float* __restrict__ w2,
                           const float* __restrict__ w3, const float* __restrict__ w4,
                           const float* __restrict__ w5, unsigned short* __restrict__ wb,
                           int* __restrict__ id_v, int* __restrict__ id_tp,
                           int* __restrict__ id_tri, int* __restrict__ ctr,
                           int* __restrict__ deg_tri, int* __restrict__ deg_tp,
                           int* __restrict__ deg_v, int* __restrict__ b_et,
                           int* __restrict__ b_tt, int* __restrict__ b_ett) {
    __shared__ int lcnt, lbase;
    int* bar = &ctr[8];
    const int tid0 = blockIdx.x * 256 + threadIdx.x;
    const int gsz = NBLK_F * 256;

    // P0: init ids + weight cvt + zero degs (ctr/bar zeroed by host memset)
    for (int x = tid0; x < NE_; x += gsz) id_v[x] = -1;
    for (int x = tid0; x < NTET_; x += gsz) id_tp[x] = -1;
    for (int x = tid0; x < NTRI_; x += gsz) id_tri[x] = -1;
    for (int x = tid0; x < 262144; x += gsz) {
        float f;
        if (x < 32768)       f = w1[x];
        else if (x < 98304)  f = w2[x - 32768];
        else if (x < 163840) f = w3[x - 98304];
        else if (x < 229376) f = w4[x - 163840];
        else                 f = w5[x - 229376];
        wb[x] = f2bf(f);
    }
    for (int x = tid0; x < CAP_TRI; x += gsz) deg_tri[x] = 0;
    for (int x = tid0; x < CAP_TP; x += gsz) deg_tp[x] = 0;
    for (int x = tid0; x < CAP_V; x += gsz) deg_v[x] = 0;
    gbar(bar, 1 * NBLK_F);

    // P1: mark_v
    for (int b = tid0; b < B_; b += gsz) {
        id_v[triples[3 * b + 0]] = -2;
        id_v[triples[3 * b + 2]] = -2;
    }
    gbar(bar, 2 * NBLK_F);

    // P2: mark_tp
    for (int e = tid0; e < EETT_; e += gsz)
        if (id_v[ett[e]] != -1) id_tp[ett[EETT_ + e]] = -2;
    gbar(bar, 3 * NBLK_F);

    // P3: compact_v || compact_tp || mark_tri (race on id_tp benign: -2 and id>=0 both != -1)
    if (blockIdx.x < NBC_V) {
        do_compact(id_v, NE_, &ctr[0], CAP_V, blockIdx.x, &lcnt, &lbase);
    } else if (blockIdx.x < NBC_V + NBC_TP) {
        do_compact(id_tp, NTET_, &ctr[1], CAP_TP, blockIdx.x - NBC_V, &lcnt, &lbase);
    } else {
        int i = (blockIdx.x - NBC_V - NBC_TP) * 256 + threadIdx.x;
        int st = (NBLK_F - NBC_V - NBC_TP) * 256;
        for (int e = i; e < ETT_; e += st)
            if (id_tp[tt[ETT_ + e]] != -1) id_tri[tt[e]] = -2;
    }
    gbar(bar, 4 * NBLK_F);

    // P4: compact_tri || filter_ett
    if (blockIdx.x < NBC_TRI) {
        do_compact(id_tri, NTRI_, &ctr[2], CAP_TRI, blockIdx.x, &lcnt, &lbase);
    } else {
        for (int ch = blockIdx.x - NBC_TRI; ch < NBF_ETT; ch += NBLK_F - NBC_TRI)
            do_filter(ett + EETT_, ett, id_tp, id_v, EETT_, deg_v, b_ett, ST_ETT, ch);
    }
    gbar(bar, 5 * NBLK_F);

    // P5: filter_et || filter_tt
    if (blockIdx.x < 352) {
        for (int ch = blockIdx.x; ch < NBF_ET; ch += 352)
            do_filter(et, et + EET_, nullptr, id_tri, EET_, deg_tri, b_et, ST_ET, ch);
    } else {
        for (int ch = blockIdx.x - 352; ch < NBF_TT; ch += NBLK_F - 352)
            do_filter(tt, tt + ETT_, id_tri, id_tp, ETT_, deg_tp, b_tt, ST_TT, ch);
    }
}

// ---------------- K3: gather-mean entity->triangle (wide grid, latency-bound) ----------------

__global__ void k_gather_tri(const int* __restrict__ ctr, const int* __restrict__ deg,
                             const int* __restrict__ bkt, const float* __restrict__ emb,
                             unsigned* __restrict__ outb) {
    const int c = min(ctr[2], CAP_TRI);
    const int lane = threadIdx.x & 63;
    int row = (blockIdx.x * blockDim.x + threadIdx.x) >> 6;
    const int nw = (gridDim.x * blockDim.x) >> 6;
    for (; row < c; row += nw) {
        int d = deg[row];
        int m = min(d, ST_ET);
        float ax = 0.f, ay = 0.f;
        for (int k = 0; k < m; ++k) {
            unsigned si = (unsigned)bkt[row * ST_ET + k];
            if (si < NE_) {
                float2 v = ((const float2*)(emb + (size_t)si * 128))[lane];
                ax += v.x; ay += v.y;
            }
        }
        float inv = (d > 0) ? 1.f / (float)d : 0.f;
        outb[(size_t)row * 64 + lane] =
            (unsigned)f2bf(ax * inv) | ((unsigned)f2bf(ay * inv) << 16);
    }
}

// ---------------- MFMA helpers (r10/r11-validated) ----------------

template<int KU>
__device__ __forceinline__ f32x4 tile_mma(const uint4* pa, int sa, const uint4* pb, int sb,
                                          int fo, f32x4 acc) {
#pragma unroll
    for (int kk = 0; kk < KU / 4; ++kk) {
        s16x8 a = *(const s16x8*)&pa[(kk * 4 + fo) ^ sa];
        s16x8 b = *(const s16x8*)&pb[(kk * 4 + fo) ^ sb];
        acc = __builtin_amdgcn_mfma_f32_16x16x32_bf16(a, b, acc, 0, 0, 0);
    }
    return acc;
}

template<int K, int ACT, bool OBF>
__device__ __forceinline__ void gemm_unit(int bx, int by, int c,
                                          const unsigned short* __restrict__ A,
                                          const unsigned short* __restrict__ Wb,
                                          const float* __restrict__ bias,
                                          void* __restrict__ Cv, int N,
                                          uint4* xs, uint4* ws) {
    constexpr int KU = K / 8;
    const int row0 = bx * 32;
    if (row0 < c) {
        const int tid = threadIdx.x;
        const int gc0 = by * 64;
#pragma unroll
        for (int it = 0; it < KU / 8; ++it) {
            int u = tid + it * 256;
            int r = u / KU, ku = u % KU;
            xs[r * KU + (ku ^ (r & 7))] = *(const uint4*)&A[(size_t)(row0 + r) * K + ku * 8];
        }
#pragma unroll
        for (int it = 0; it < KU / 4; ++it) {
            int u = tid + it * 256;
            int r = u / KU, ku = u % KU;
            ws[r * KU + (ku ^ (r & 7))] = *(const uint4*)&Wb[(size_t)(gc0 + r) * K + ku * 8];
        }
        __syncthreads();
        const int w = tid >> 6, l = tid & 63;
        const int wr = (w >> 1) * 16, wc0 = (w & 1) * 32;
        const int fr = l & 15, fo = l >> 4;
        const int ra = wr + fr, rb0 = wc0 + fr, rb1 = wc0 + 16 + fr;
        f32x4 z = {0.f, 0.f, 0.f, 0.f};
        f32x4 acc0 = tile_mma<KU>(xs + ra * KU, ra & 7, ws + rb0 * KU, rb0 & 7, fo, z);
        f32x4 acc1 = tile_mma<KU>(xs + ra * KU, ra & 7, ws + rb1 * KU, rb1 & 7, fo, z);
        const int col0 = gc0 + wc0 + fr, col1 = col0 + 16;
        const float bb0 = bias[col0], bb1 = bias[col1];
#pragma unroll
        for (int j = 0; j < 4; ++j) {
            int grow = row0 + wr + fo * 4 + j;
            if (grow < c) {
                float v0 = acc0[j] + bb0;
                float v1 = acc1[j] + bb1;
                if (ACT == 1) { v0 = gelu_exact(v0); v1 = gelu_exact(v1); }
                if (OBF) {
                    ((unsigned short*)Cv)[(size_t)grow * N + col0] = f2bf(v0);
                    ((unsigned short*)Cv)[(size_t)grow * N + col1] = f2bf(v1);
                } else {
                    ((float*)Cv)[(size_t)grow * N + col0] = v0;
                    ((float*)Cv)[(size_t)grow * N + col1] = v1;
                }
            }
        }
        __syncthreads();
    }
}

__device__ __forceinline__ void tet1_unit(int bx, int by, int c,
                                          const int* __restrict__ deg, const int* __restrict__ bkt,
                                          const unsigned short* __restrict__ tri_c,
                                          const unsigned short* __restrict__ Wb,
                                          const float* __restrict__ bias,
                                          unsigned short* __restrict__ h_tet,
                                          uint4* xs, uint4* ws) {
    constexpr int KU = 32;
    const int row0 = bx * 32;
    if (row0 < c) {
        const int tid = threadIdx.x, lane = tid & 63, wv = tid >> 6;
        const int gc0 = by * 64;
        for (int rr = wv * 8; rr < wv * 8 + 8; ++rr) {
            int row = row0 + rr;
            float a0 = 0.f, a1 = 0.f, a2 = 0.f, a3 = 0.f;
            int d = 0;
            if (row < c) {
                d = deg[row];
                int m = min(d, ST_TT);
                for (int k = 0; k < m; ++k) {
                    unsigned si = (unsigned)bkt[row * ST_TT + k];
                    if (si < CAP_TRI) {
                        uint2 p = ((const uint2*)(tri_c + (size_t)si * 256))[lane];
                        a0 += bf2f(p.x & 0xffffu); a1 += bf2f(p.x >> 16);
                        a2 += bf2f(p.y & 0xffffu); a3 += bf2f(p.y >> 16);
                    }
                }
            }
            float inv = (d > 0) ? 1.f / (float)d : 0.f;
            uint2 o;
            o.x = (unsigned)f2bf(a0 * inv) | ((unsigned)f2bf(a1 * inv) << 16);
            o.y = (unsigned)f2bf(a2 * inv) | ((unsigned)f2bf(a3 * inv) << 16);
            int col0 = lane * 4;
            int ku = col0 >> 3, off = col0 & 7;
            *(uint2*)((unsigned short*)&xs[rr * KU + (ku ^ (rr & 7))] + off) = o;
        }
#pragma unroll
        for (int it = 0; it < KU / 4; ++it) {
            int u = tid + it * 256;
            int r = u / KU, ku = u % KU;
            ws[r * KU + (ku ^ (r & 7))] = *(const uint4*)&Wb[(size_t)(gc0 + r) * 256 + ku * 8];
        }
        __syncthreads();
        const int w = tid >> 6;
        const int wr = (w >> 1) * 16, wc0 = (w & 1) * 32;
        const int fr = lane & 15, fo = lane >> 4;
        const int ra = wr + fr, rb0 = wc0 + fr, rb1 = wc0 + 16 + fr;
        f32x4 z = {0.f, 0.f, 0.f, 0.f};
        f32x4 acc0 = tile_mma<KU>(xs + ra * KU, ra & 7, ws + rb0 * KU, rb0 & 7, fo, z);
        f32x4 acc1 = tile_mma<KU>(xs + ra * KU, ra & 7, ws + rb1 * KU, rb1 & 7, fo, z);
        const int col0 = gc0 + wc0 + fr, col1 = col0 + 16;
        const float bb0 = bias[col0], bb1 = bias[col1];
#pragma unroll
        for (int j = 0; j < 4; ++j) {
            int grow = row0 + wr + fo * 4 + j;
            if (grow < c) {
                h_tet[(size_t)grow * 256 + col0] = f2bf(gelu_exact(acc0[j] + bb0));
                h_tet[(size_t)grow * 256 + col1] = f2bf(gelu_exact(acc1[j] + bb1));
            }
        }
        __syncthreads();
    }
}

// ---------------- K4: mega back-end (6 phases, 5 barriers) ----------------

__launch_bounds__(256, 2)
__global__ void mega_back(const int* __restrict__ ctr, const unsigned short* __restrict__ wb,
                          const unsigned short* __restrict__ tri_agg,
                          unsigned short* __restrict__ h_tri, unsigned short* __restrict__ tri_c,
                          const int* __restrict__ deg_tp, const int* __restrict__ b_tt,
                          unsigned short* __restrict__ h_tet, unsigned short* __restrict__ y_tet,
                          float* __restrict__ tet_proj,
                          const int* __restrict__ deg_v, const int* __restrict__ b_ett,
                          const int* __restrict__ id_v,
                          const float* __restrict__ g2b1, const float* __restrict__ g2b2,
                          const float* __restrict__ g3b1, const float* __restrict__ g3b2,
                          const float* __restrict__ teb,
                          const float* __restrict__ emb, const float* __restrict__ rel,
                          const float* __restrict__ lnw, const float* __restrict__ lnb,
                          const float* __restrict__ alpha, const float* __restrict__ gamma,
                          const int* __restrict__ triples, float* __restrict__ out,
                          int* __restrict__ barp) {
    __shared__ __align__(16) uint4 xs[32 * 32];   // 16 KB
    __shared__ __align__(16) uint4 ws[64 * 32];   // 32 KB
    const int c_tri = min(ctr[2], CAP_TRI);
    const int c_tp = min(ctr[1], CAP_TP);

    // P0: tri L1 (K=128, gelu) -> h_tri ; units 384x4
    for (int u = blockIdx.x; u < (CAP_TRI / 32) * 4; u += NBLK_B)
        gemm_unit<128, 1, true>(u % (CAP_TRI / 32), u / (CAP_TRI / 32), c_tri,
                                tri_agg, wb + WB_G2W1, g2b1, h_tri, TRIH_, xs, ws);
    gbar(barp, 1 * NBLK_B);

    // P1: tri L2 (K=256) -> tri_c
    for (int u = blockIdx.x; u < (CAP_TRI / 32) * 4; u += NBLK_B)
        gemm_unit<256, 0, true>(u % (CAP_TRI / 32), u / (CAP_TRI / 32), c_tri,
                                h_tri, wb + WB_G2W2, g2b2, tri_c, TRIH_, xs, ws);
    gbar(barp, 2 * NBLK_B);

    // P2: tet gather + L1 -> h_tet ; units 256x4
    for (int u = blockIdx.x; u < (CAP_TP / 32) * 4; u += NBLK_B)
        tet1_unit(u % (CAP_TP / 32), u / (CAP_TP / 32), c_tp,
                  deg_tp, b_tt, tri_c, wb + WB_G3W1, g3b1, h_tet, xs, ws);
    gbar(barp, 3 * NBLK_B);

    // P3: tet L2 -> y_tet
    for (int u = blockIdx.x; u < (CAP_TP / 32) * 4; u += NBLK_B)
        gemm_unit<256, 0, true>(u % (CAP_TP / 32), u / (CAP_TP / 32), c_tp,
                                h_tet, wb + WB_G3W2, g3b2, y_tet, TETH_, xs, ws);
    gbar(barp, 4 * NBLK_B);

    // P4: proj -> tet_proj (f32) ; units 256x2
    for (int u = blockIdx.x; u < (CAP_TP / 32) * 2; u += NBLK_B)
        gemm_unit<256, 0, false>(u % (CAP_TP / 32), u / (CAP_TP / 32), c_tp,
                                 y_tet, wb + WB_TE, teb, tet_proj, D_, xs, ws);
    gbar(barp, 5 * NBLK_B);

    // P5: final (v-gather + mean + LN + fusion + TransE), wave per triple
    {
        const int lane = threadIdx.x & 63;
        int gw = blockIdx.x * 4 + (threadIdx.x >> 6);
        const int nw = NBLK_B * 4;
        float a0 = alpha[0], a1 = alpha[1];
        float m = fmaxf(a0, a1);
        float e0 = expf(a0 - m), e1 = expf(a1 - m);
        float w0 = e0 / (e0 + e1), w1 = e1 / (e0 + e1);
        for (int b = gw; b < B_; b += nw) {
            int h = triples[b * 3 + 0];
            int r = triples[b * 3 + 1];
            int t = triples[b * 3 + 2];
            int jh = id_v[h]; jh = (jh >= 0 && jh < CAP_V) ? jh : 0;
            int jt = id_v[t]; jt = (jt >= 0 && jt < CAP_V) ? jt : 0;
            float2 xh = make_float2(0.f, 0.f), xt = make_float2(0.f, 0.f);
            {
                int d = deg_v[jh], mm = min(d, ST_ETT);
                for (int k = 0; k < mm; ++k) {
                    unsigned si = (unsigned)b_ett[jh * ST_ETT + k];
                    if (si < CAP_TP) {
                        float2 v = ((const float2*)(tet_proj + (size_t)si * 128))[lane];
                        xh.x += v.x; xh.y += v.y;
                    }
                }
                float inv = (d > 0) ? 1.f / (float)d : 0.f;
                xh.x *= inv; xh.y *= inv;
            }
            {
                int d = deg_v[jt], mm = min(d, ST_ETT);
                for (int k = 0; k < mm; ++k) {
                    unsigned si = (unsigned)b_ett[jt * ST_ETT + k];
                    if (si < CAP_TP) {
                        float2 v = ((const float2*)(tet_proj + (size_t)si * 128))[lane];
                        xt.x += v.x; xt.y += v.y;
                    }
                }
                float inv = (d > 0) ? 1.f / (float)d : 0.f;
                xt.x *= inv; xt.y *= inv;
            }
            float sh = xh.x + xh.y, st = xt.x + xt.y;
#pragma unroll
            for (int o = 32; o >= 1; o >>= 1) { sh += __shfl_xor(sh, o, 64); st += __shfl_xor(st, o, 64); }
            float muh = sh * (1.f / 128.f), mut = st * (1.f / 128.f);
            float2 dh = make_float2(xh.x - muh, xh.y - muh);
            float2 dt = make_float2(xt.x - mut, xt.y - mut);
            float vh_ = dh.x * dh.x + dh.y * dh.y, vt_ = dt.x * dt.x + dt.y * dt.y;
#pragma unroll
            for (int o = 32; o >= 1; o >>= 1) { vh_ += __shfl_xor(vh_, o, 64); vt_ += __shfl_xor(vt_, o, 64); }
            float rsh = rsqrtf(vh_ * (1.f / 128.f) + 1e-5f);
            float rst = rsqrtf(vt_ * (1.f / 128.f) + 1e-5f);
            float2 lw = ((const float2*)lnw)[lane];
            float2 lb = ((const float2*)lnb)[lane];
            float2 lnh = make_float2(dh.x * rsh * lw.x + lb.x, dh.y * rsh * lw.y + lb.y);
            float2 lnt = make_float2(dt.x * rst * lw.x + lb.x, dt.y * rst * lw.y + lb.y);
            float2 eh = ((const float2*)emb)[(size_t)h * 64 + lane];
            float2 etv = ((const float2*)emb)[(size_t)t * 64 + lane];
            float2 rr = ((const float2*)rel)[(size_t)r * 64 + lane];
            float dx = (w0 * eh.x + w1 * lnh.x) + rr.x - (w0 * etv.x + w1 * lnt.x);
            float dy = (w0 * eh.y + w1 * lnh.y) + rr.y - (w0 * etv.y + w1 * lnt.y);
            float ss = dx * dx + dy * dy;
#pragma unroll
            for (int o = 32; o >= 1; o >>= 1) ss += __shfl_xor(ss, o, 64);
            if (lane == 0) out[b] = gamma[0] - sqrtf(ss);
        }
    }
}

// ---------------- host launcher ----------------

extern "C" void kernel_launch(void* const* d_in, const int* in_sizes, int n_in,
                              void* d_out, int out_size, void* d_ws, size_t ws_size,
                              hipStream_t stream) {
    const float* entity_emb = (const float*)d_in[0];
    const float* relation_emb = (const float*)d_in[1];
    const float* g2_w1 = (const float*)d_in[2];
    const float* g2_b1 = (const float*)d_in[3];
    const float* g2_w2 = (const float*)d_in[4];
    const float* g2_b2 = (const float*)d_in[5];
    const float* g3_w1 = (const float*)d_in[6];
    const float* g3_b1 = (const float*)d_in[7];
    const float* g3_w2 = (const float*)d_in[8];
    const float* g3_b2 = (const float*)d_in[9];
    const float* te_w = (const float*)d_in[10];
    const float* te_b = (const float*)d_in[11];
    const float* ln_w = (const float*)d_in[12];
    const float* ln_b = (const float*)d_in[13];
    const float* alpha = (const float*)d_in[14];
    const float* gamma = (const float*)d_in[15];
    const int* triples = (const int*)d_in[16];
    const int* et = (const int*)d_in[17];
    const int* tt = (const int*)d_in[18];
    const int* ett = (const int*)d_in[19];
    float* out = (float*)d_out;

    char* base = (char*)d_ws;
    size_t off = 0;
    auto take = [&](size_t bytes) -> void* {
        void* p = base + off;
        off = (off + bytes + 255) & ~(size_t)255;
        return p;
    };
    int* id_v = (int*)take((size_t)NE_ * 4);
    int* id_tp = (int*)take((size_t)NTET_ * 4);
    int* id_tri = (int*)take((size_t)NTRI_ * 4);
    int* ctr = (int*)take(64);
    int* deg_tri = (int*)take((size_t)CAP_TRI * 4);
    int* deg_tp = (int*)take((size_t)CAP_TP * 4);
    int* deg_v = (int*)take((size_t)CAP_V * 4);
    int* b_et = (int*)take((size_t)CAP_TRI * ST_ET * 4);
    int* b_tt = (int*)take((size_t)CAP_TP * ST_TT * 4);
    int* b_ett = (int*)take((size_t)CAP_V * ST_ETT * 4);
    unsigned short* wb = (unsigned short*)take((size_t)262144 * 2);
    unsigned short* tri_agg = (unsigned short*)take((size_t)CAP_TRI * D_ * 2);
    unsigned short* h_tri = (unsigned short*)take((size_t)CAP_TRI * TRIH_ * 2);
    unsigned short* tri_c = (unsigned short*)take((size_t)CAP_TRI * TRIH_ * 2);
    unsigned short* h_tet = (unsigned short*)take((size_t)CAP_TP * TETH_ * 2);
    unsigned short* y_tet = (unsigned short*)take((size_t)CAP_TP * TETH_ * 2);
    float* tet_proj = (float*)take((size_t)CAP_TP * D_ * 4);
    if (off > ws_size) return;  // workspace too small -> visible validation failure

    hipMemsetAsync(ctr, 0, 64, stream);  // counters + both spin-barrier words

    mega_front<<<NBLK_F, 256, 0, stream>>>(triples, et, tt, ett,
                                           g2_w1, g2_w2, g3_w1, g3_w2, te_w, wb,
                                           id_v, id_tp, id_tri, ctr,
                                           deg_tri, deg_tp, deg_v, b_et, b_tt, b_ett);
    k_gather_tri<<<2048, 256, 0, stream>>>(ctr, deg_tri, b_et, entity_emb, (unsigned*)tri_agg);
    mega_back<<<NBLK_B, 256, 0, stream>>>(ctr, wb, tri_agg, h_tri, tri_c,
                                          deg_tp, b_tt, h_tet, y_tet, tet_proj,
                                          deg_v, b_ett, id_v,
                                          g2_b1, g2_b2, g3_b1, g3_b2, te_b,
                                          entity_emb, relation_emb, ln_w, ln_b,
                                          alpha, gamma, triples, out, &ctr[9]);
}

// Round 15
// 507.301 us; speedup vs baseline: 1.5153x; 1.4969x over previous
//
#include <hip/hip_runtime.h>
#include <cmath>

#define NE_     200000
#define NR_     500
#define D_      128
#define TRIH_   256
#define TETH_   256
#define NTRI_   500000
#define NTET_   200000
#define B_      8192
#define EET_    1500000
#define ETT_    800000
#define EETT_   800000

#define CAP_V   2048
#define CAP_TP  8192
#define CAP_TRI 12288

#define ST_ET   64
#define ST_TT   32
#define ST_ETT  32

#define COARSEN 8
#define CHUNK   (256 * COARSEN)

#define NBC_V   ((NE_   + CHUNK - 1) / CHUNK)   // 98
#define NBC_TP  ((NTET_ + CHUNK - 1) / CHUNK)   // 98
#define NBC_TRI ((NTRI_ + CHUNK - 1) / CHUNK)   // 245
#define NBF_ET  ((EET_  + CHUNK - 1) / CHUNK)   // 733
#define NBF_TT  ((ETT_  + CHUNK - 1) / CHUNK)   // 391
#define NBF_ETT ((EETT_ + CHUNK - 1) / CHUNK)   // 391

#define NBLK_F  512
#define NBLK_B  512

#define WB_G2W1 0
#define WB_G2W2 32768
#define WB_G3W1 98304
#define WB_G3W2 163840
#define WB_TE   229376

// ctr: [0]=c_v [1]=c_tp [2]=c_tri [8]=barF [9]=barB  (zeroed via hipMemsetAsync)

typedef float f32x4 __attribute__((ext_vector_type(4)));
typedef short s16x8 __attribute__((ext_vector_type(8)));

__device__ __forceinline__ float gelu_exact(float v) {
    return 0.5f * v * (1.0f + erff(v * 0.70710678118654752f));
}

__device__ __forceinline__ unsigned short f2bf(float f) {
    unsigned int u = __float_as_uint(f);
    unsigned int r = (u + 0x7fffu + ((u >> 16) & 1u)) >> 16;
    return (unsigned short)r;
}

__device__ __forceinline__ float bf2f(unsigned int u) {
    return __uint_as_float(u << 16);
}

__device__ __forceinline__ int wave_rank_emit(bool pred, int* lcnt, int lane) {
    unsigned long long mask = __ballot(pred);
    int rank = __popcll(mask & ((1ull << lane) - 1ull));
    int total = __popcll(mask);
    int wb = 0;
    if (lane == 0 && total) wb = atomicAdd(lcnt, total);
    wb = __shfl(wb, 0, 64);
    return pred ? (wb + rank) : -1;
}

// device-wide spin barrier, FIXED (r14 post-mortem): relaxed polls (no per-poll
// L2 invalidate), exactly one release fence before arrival and one acquire
// fence after exit. Relaxed agent-scope atomics still access the coherence
// point (visible across XCDs); the fences do the cache maintenance ONCE.
__device__ __forceinline__ void gbar(int* bar, int target) {
    __syncthreads();
    if (threadIdx.x == 0) {
        __builtin_amdgcn_fence(__ATOMIC_RELEASE, "agent");   // wb our XCD's L2 once
        __hip_atomic_fetch_add(bar, 1, __ATOMIC_RELAXED, __HIP_MEMORY_SCOPE_AGENT);
        while (__hip_atomic_load(bar, __ATOMIC_RELAXED, __HIP_MEMORY_SCOPE_AGENT) < target)
            __builtin_amdgcn_s_sleep(32);
        __builtin_amdgcn_fence(__ATOMIC_ACQUIRE, "agent");   // inv L1/L2 once
    }
    __syncthreads();
}

// ---------------- building blocks (r11-validated bodies) ----------------

__device__ void do_compact(int* __restrict__ arr, int n, int* __restrict__ g, int cap,
                           int bid, int* lcnt, int* lbase) {
    if (threadIdx.x == 0) *lcnt = 0;
    __syncthreads();
    const int lane = threadIdx.x & 63;
    const int base = bid * CHUNK;
    int pos[COARSEN];
#pragma unroll
    for (int u = 0; u < COARSEN; ++u) {
        int e = base + u * 256 + threadIdx.x;
        bool pred = (e < n) && (arr[e] == -2);
        pos[u] = wave_rank_emit(pred, lcnt, lane);
    }
    __syncthreads();
    if (threadIdx.x == 0) *lbase = *lcnt ? atomicAdd(g, *lcnt) : 0;
    __syncthreads();
    const int b0 = *lbase;
#pragma unroll
    for (int u = 0; u < COARSEN; ++u) {
        if (pos[u] >= 0) {
            int e = base + u * 256 + threadIdx.x;
            int idx = b0 + pos[u];
            arr[e] = (idx < cap) ? idx : -1;
        }
    }
}

__device__ void do_filter(const int* __restrict__ e0, const int* __restrict__ e1,
                          const int* __restrict__ map0, const int* __restrict__ map1,
                          int n, int* __restrict__ deg, int* __restrict__ bkt,
                          int stride, int bid) {
#pragma unroll
    for (int u = 0; u < COARSEN; ++u) {
        int e = bid * CHUNK + u * 256 + threadIdx.x;
        if (e < n) {
            int m1 = map1[e1[e]];
            if (m1 >= 0) {
                int src = map0 ? map0[e0[e]] : e0[e];
                if (src >= 0) {
                    int slot = atomicAdd(&deg[m1], 1);
                    if (slot < stride) bkt[m1 * stride + slot] = src;
                }
            }
        }
    }
}

// ---------------- K2: mega front-end (6 phases, 5 barriers) ----------------

__launch_bounds__(256, 2)
__global__ void mega_front(const int* __restrict__ triples, const int* __restrict__ et,
                           const int* __restrict__ tt, const int* __restrict__ ett,
                           const float* __restrict__ w1, const float* __restrict__ w2,
                           const float* __restrict__ w3, const float* __restrict__ w4,
                           const float* __restrict__ w5, unsigned short* __restrict__ wb,
                           int* __restrict__ id_v, int* __restrict__ id_tp,
                           int* __restrict__ id_tri, int* __restrict__ ctr,
                           int* __restrict__ deg_tri, int* __restrict__ deg_tp,
                           int* __restrict__ deg_v, int* __restrict__ b_et,
                           int* __restrict__ b_tt, int* __restrict__ b_ett) {
    __shared__ int lcnt, lbase;
    int* bar = &ctr[8];
    const int tid0 = blockIdx.x * 256 + threadIdx.x;
    const int gsz = NBLK_F * 256;

    // P0: init ids + weight cvt + zero degs (ctr/bar zeroed by host memset)
    for (int x = tid0; x < NE_; x += gsz) id_v[x] = -1;
    for (int x = tid0; x < NTET_; x += gsz) id_tp[x] = -1;
    for (int x = tid0; x < NTRI_; x += gsz) id_tri[x] = -1;
    for (int x = tid0; x < 262144; x += gsz) {
        float f;
        if (x < 32768)       f = w1[x];
        else if (x < 98304)  f = w2[x - 32768];
        else if (x < 163840) f = w3[x - 98304];
        else if (x < 229376) f = w4[x - 163840];
        else                 f = w5[x - 229376];
        wb[x] = f2bf(f);
    }
    for (int x = tid0; x < CAP_TRI; x += gsz) deg_tri[x] = 0;
    for (int x = tid0; x < CAP_TP; x += gsz) deg_tp[x] = 0;
    for (int x = tid0; x < CAP_V; x += gsz) deg_v[x] = 0;
    gbar(bar, 1 * NBLK_F);

    // P1: mark_v
    for (int b = tid0; b < B_; b += gsz) {
        id_v[triples[3 * b + 0]] = -2;
        id_v[triples[3 * b + 2]] = -2;
    }
    gbar(bar, 2 * NBLK_F);

    // P2: mark_tp
    for (int e = tid0; e < EETT_; e += gsz)
        if (id_v[ett[e]] != -1) id_tp[ett[EETT_ + e]] = -2;
    gbar(bar, 3 * NBLK_F);

    // P3: compact_v || compact_tp || mark_tri (race on id_tp benign: -2 and id>=0 both != -1)
    if (blockIdx.x < NBC_V) {
        do_compact(id_v, NE_, &ctr[0], CAP_V, blockIdx.x, &lcnt, &lbase);
    } else if (blockIdx.x < NBC_V + NBC_TP) {
        do_compact(id_tp, NTET_, &ctr[1], CAP_TP, blockIdx.x - NBC_V, &lcnt, &lbase);
    } else {
        int i = (blockIdx.x - NBC_V - NBC_TP) * 256 + threadIdx.x;
        int st = (NBLK_F - NBC_V - NBC_TP) * 256;
        for (int e = i; e < ETT_; e += st)
            if (id_tp[tt[ETT_ + e]] != -1) id_tri[tt[e]] = -2;
    }
    gbar(bar, 4 * NBLK_F);

    // P4: compact_tri || filter_ett
    if (blockIdx.x < NBC_TRI) {
        do_compact(id_tri, NTRI_, &ctr[2], CAP_TRI, blockIdx.x, &lcnt, &lbase);
    } else {
        for (int ch = blockIdx.x - NBC_TRI; ch < NBF_ETT; ch += NBLK_F - NBC_TRI)
            do_filter(ett + EETT_, ett, id_tp, id_v, EETT_, deg_v, b_ett, ST_ETT, ch);
    }
    gbar(bar, 5 * NBLK_F);

    // P5: filter_et || filter_tt
    if (blockIdx.x < 352) {
        for (int ch = blockIdx.x; ch < NBF_ET; ch += 352)
            do_filter(et, et + EET_, nullptr, id_tri, EET_, deg_tri, b_et, ST_ET, ch);
    } else {
        for (int ch = blockIdx.x - 352; ch < NBF_TT; ch += NBLK_F - 352)
            do_filter(tt, tt + ETT_, id_tri, id_tp, ETT_, deg_tp, b_tt, ST_TT, ch);
    }
}

// ---------------- K3: gather-mean entity->triangle (wide grid, latency-bound) ----------------

__global__ void k_gather_tri(const int* __restrict__ ctr, const int* __restrict__ deg,
                             const int* __restrict__ bkt, const float* __restrict__ emb,
                             unsigned* __restrict__ outb) {
    const int c = min(ctr[2], CAP_TRI);
    const int lane = threadIdx.x & 63;
    int row = (blockIdx.x * blockDim.x + threadIdx.x) >> 6;
    const int nw = (gridDim.x * blockDim.x) >> 6;
    for (; row < c; row += nw) {
        int d = deg[row];
        int m = min(d, ST_ET);
        float ax = 0.f, ay = 0.f;
        for (int k = 0; k < m; ++k) {
            unsigned si = (unsigned)bkt[row * ST_ET + k];
            if (si < NE_) {
                float2 v = ((const float2*)(emb + (size_t)si * 128))[lane];
                ax += v.x; ay += v.y;
            }
        }
        float inv = (d > 0) ? 1.f / (float)d : 0.f;
        outb[(size_t)row * 64 + lane] =
            (unsigned)f2bf(ax * inv) | ((unsigned)f2bf(ay * inv) << 16);
    }
}

// ---------------- MFMA helpers (r10/r11-validated) ----------------

template<int KU>
__device__ __forceinline__ f32x4 tile_mma(const uint4* pa, int sa, const uint4* pb, int sb,
                                          int fo, f32x4 acc) {
#pragma unroll
    for (int kk = 0; kk < KU / 4; ++kk) {
        s16x8 a = *(const s16x8*)&pa[(kk * 4 + fo) ^ sa];
        s16x8 b = *(const s16x8*)&pb[(kk * 4 + fo) ^ sb];
        acc = __builtin_amdgcn_mfma_f32_16x16x32_bf16(a, b, acc, 0, 0, 0);
    }
    return acc;
}

template<int K, int ACT, bool OBF>
__device__ __forceinline__ void gemm_unit(int bx, int by, int c,
                                          const unsigned short* __restrict__ A,
                                          const unsigned short* __restrict__ Wb,
                                          const float* __restrict__ bias,
                                          void* __restrict__ Cv, int N,
                                          uint4* xs, uint4* ws) {
    constexpr int KU = K / 8;
    const int row0 = bx * 32;
    if (row0 < c) {
        const int tid = threadIdx.x;
        const int gc0 = by * 64;
#pragma unroll
        for (int it = 0; it < KU / 8; ++it) {
            int u = tid + it * 256;
            int r = u / KU, ku = u % KU;
            xs[r * KU + (ku ^ (r & 7))] = *(const uint4*)&A[(size_t)(row0 + r) * K + ku * 8];
        }
#pragma unroll
        for (int it = 0; it < KU / 4; ++it) {
            int u = tid + it * 256;
            int r = u / KU, ku = u % KU;
            ws[r * KU + (ku ^ (r & 7))] = *(const uint4*)&Wb[(size_t)(gc0 + r) * K + ku * 8];
        }
        __syncthreads();
        const int w = tid >> 6, l = tid & 63;
        const int wr = (w >> 1) * 16, wc0 = (w & 1) * 32;
        const int fr = l & 15, fo = l >> 4;
        const int ra = wr + fr, rb0 = wc0 + fr, rb1 = wc0 + 16 + fr;
        f32x4 z = {0.f, 0.f, 0.f, 0.f};
        f32x4 acc0 = tile_mma<KU>(xs + ra * KU, ra & 7, ws + rb0 * KU, rb0 & 7, fo, z);
        f32x4 acc1 = tile_mma<KU>(xs + ra * KU, ra & 7, ws + rb1 * KU, rb1 & 7, fo, z);
        const int col0 = gc0 + wc0 + fr, col1 = col0 + 16;
        const float bb0 = bias[col0], bb1 = bias[col1];
#pragma unroll
        for (int j = 0; j < 4; ++j) {
            int grow = row0 + wr + fo * 4 + j;
            if (grow < c) {
                float v0 = acc0[j] + bb0;
                float v1 = acc1[j] + bb1;
                if (ACT == 1) { v0 = gelu_exact(v0); v1 = gelu_exact(v1); }
                if (OBF) {
                    ((unsigned short*)Cv)[(size_t)grow * N + col0] = f2bf(v0);
                    ((unsigned short*)Cv)[(size_t)grow * N + col1] = f2bf(v1);
                } else {
                    ((float*)Cv)[(size_t)grow * N + col0] = v0;
                    ((float*)Cv)[(size_t)grow * N + col1] = v1;
                }
            }
        }
        __syncthreads();
    }
}

__device__ __forceinline__ void tet1_unit(int bx, int by, int c,
                                          const int* __restrict__ deg, const int* __restrict__ bkt,
                                          const unsigned short* __restrict__ tri_c,
                                          const unsigned short* __restrict__ Wb,
                                          const float* __restrict__ bias,
                                          unsigned short* __restrict__ h_tet,
                                          uint4* xs, uint4* ws) {
    constexpr int KU = 32;
    const int row0 = bx * 32;
    if (row0 < c) {
        const int tid = threadIdx.x, lane = tid & 63, wv = tid >> 6;
        const int gc0 = by * 64;
        for (int rr = wv * 8; rr < wv * 8 + 8; ++rr) {
            int row = row0 + rr;
            float a0 = 0.f, a1 = 0.f, a2 = 0.f, a3 = 0.f;
            int d = 0;
            if (row < c) {
                d = deg[row];
                int m = min(d, ST_TT);
                for (int k = 0; k < m; ++k) {
                    unsigned si = (unsigned)bkt[row * ST_TT + k];
                    if (si < CAP_TRI) {
                        uint2 p = ((const uint2*)(tri_c + (size_t)si * 256))[lane];
                        a0 += bf2f(p.x & 0xffffu); a1 += bf2f(p.x >> 16);
                        a2 += bf2f(p.y & 0xffffu); a3 += bf2f(p.y >> 16);
                    }
                }
            }
            float inv = (d > 0) ? 1.f / (float)d : 0.f;
            uint2 o;
            o.x = (unsigned)f2bf(a0 * inv) | ((unsigned)f2bf(a1 * inv) << 16);
            o.y = (unsigned)f2bf(a2 * inv) | ((unsigned)f2bf(a3 * inv) << 16);
            int col0 = lane * 4;
            int ku = col0 >> 3, off = col0 & 7;
            *(uint2*)((unsigned short*)&xs[rr * KU + (ku ^ (rr & 7))] + off) = o;
        }
#pragma unroll
        for (int it = 0; it < KU / 4; ++it) {
            int u = tid + it * 256;
            int r = u / KU, ku = u % KU;
            ws[r * KU + (ku ^ (r & 7))] = *(const uint4*)&Wb[(size_t)(gc0 + r) * 256 + ku * 8];
        }
        __syncthreads();
        const int w = tid >> 6;
        const int wr = (w >> 1) * 16, wc0 = (w & 1) * 32;
        const int fr = lane & 15, fo = lane >> 4;
        const int ra = wr + fr, rb0 = wc0 + fr, rb1 = wc0 + 16 + fr;
        f32x4 z = {0.f, 0.f, 0.f, 0.f};
        f32x4 acc0 = tile_mma<KU>(xs + ra * KU, ra & 7, ws + rb0 * KU, rb0 & 7, fo, z);
        f32x4 acc1 = tile_mma<KU>(xs + ra * KU, ra & 7, ws + rb1 * KU, rb1 & 7, fo, z);
        const int col0 = gc0 + wc0 + fr, col1 = col0 + 16;
        const float bb0 = bias[col0], bb1 = bias[col1];
#pragma unroll
        for (int j = 0; j < 4; ++j) {
            int grow = row0 + wr + fo * 4 + j;
            if (grow < c) {
                h_tet[(size_t)grow * 256 + col0] = f2bf(gelu_exact(acc0[j] + bb0));
                h_tet[(size_t)grow * 256 + col1] = f2bf(gelu_exact(acc1[j] + bb1));
            }
        }
        __syncthreads();
    }
}

// ---------------- K4: mega back-end (6 phases, 5 barriers) ----------------

__launch_bounds__(256, 2)
__global__ void mega_back(const int* __restrict__ ctr, const unsigned short* __restrict__ wb,
                          const unsigned short* __restrict__ tri_agg,
                          unsigned short* __restrict__ h_tri, unsigned short* __restrict__ tri_c,
                          const int* __restrict__ deg_tp, const int* __restrict__ b_tt,
                          unsigned short* __restrict__ h_tet, unsigned short* __restrict__ y_tet,
                          float* __restrict__ tet_proj,
                          const int* __restrict__ deg_v, const int* __restrict__ b_ett,
                          const int* __restrict__ id_v,
                          const float* __restrict__ g2b1, const float* __restrict__ g2b2,
                          const float* __restrict__ g3b1, const float* __restrict__ g3b2,
                          const float* __restrict__ teb,
                          const float* __restrict__ emb, const float* __restrict__ rel,
                          const float* __restrict__ lnw, const float* __restrict__ lnb,
                          const float* __restrict__ alpha, const float* __restrict__ gamma,
                          const int* __restrict__ triples, float* __restrict__ out,
                          int* __restrict__ barp) {
    __shared__ __align__(16) uint4 xs[32 * 32];   // 16 KB
    __shared__ __align__(16) uint4 ws[64 * 32];   // 32 KB
    const int c_tri = min(ctr[2], CAP_TRI);
    const int c_tp = min(ctr[1], CAP_TP);

    // P0: tri L1 (K=128, gelu) -> h_tri ; units 384x4
    for (int u = blockIdx.x; u < (CAP_TRI / 32) * 4; u += NBLK_B)
        gemm_unit<128, 1, true>(u % (CAP_TRI / 32), u / (CAP_TRI / 32), c_tri,
                                tri_agg, wb + WB_G2W1, g2b1, h_tri, TRIH_, xs, ws);
    gbar(barp, 1 * NBLK_B);

    // P1: tri L2 (K=256) -> tri_c
    for (int u = blockIdx.x; u < (CAP_TRI / 32) * 4; u += NBLK_B)
        gemm_unit<256, 0, true>(u % (CAP_TRI / 32), u / (CAP_TRI / 32), c_tri,
                                h_tri, wb + WB_G2W2, g2b2, tri_c, TRIH_, xs, ws);
    gbar(barp, 2 * NBLK_B);

    // P2: tet gather + L1 -> h_tet ; units 256x4
    for (int u = blockIdx.x; u < (CAP_TP / 32) * 4; u += NBLK_B)
        tet1_unit(u % (CAP_TP / 32), u / (CAP_TP / 32), c_tp,
                  deg_tp, b_tt, tri_c, wb + WB_G3W1, g3b1, h_tet, xs, ws);
    gbar(barp, 3 * NBLK_B);

    // P3: tet L2 -> y_tet
    for (int u = blockIdx.x; u < (CAP_TP / 32) * 4; u += NBLK_B)
        gemm_unit<256, 0, true>(u % (CAP_TP / 32), u / (CAP_TP / 32), c_tp,
                                h_tet, wb + WB_G3W2, g3b2, y_tet, TETH_, xs, ws);
    gbar(barp, 4 * NBLK_B);

    // P4: proj -> tet_proj (f32) ; units 256x2
    for (int u = blockIdx.x; u < (CAP_TP / 32) * 2; u += NBLK_B)
        gemm_unit<256, 0, false>(u % (CAP_TP / 32), u / (CAP_TP / 32), c_tp,
                                 y_tet, wb + WB_TE, teb, tet_proj, D_, xs, ws);
    gbar(barp, 5 * NBLK_B);

    // P5: final (v-gather + mean + LN + fusion + TransE), wave per triple
    {
        const int lane = threadIdx.x & 63;
        int gw = blockIdx.x * 4 + (threadIdx.x >> 6);
        const int nw = NBLK_B * 4;
        float a0 = alpha[0], a1 = alpha[1];
        float m = fmaxf(a0, a1);
        float e0 = expf(a0 - m), e1 = expf(a1 - m);
        float w0 = e0 / (e0 + e1), w1 = e1 / (e0 + e1);
        for (int b = gw; b < B_; b += nw) {
            int h = triples[b * 3 + 0];
            int r = triples[b * 3 + 1];
            int t = triples[b * 3 + 2];
            int jh = id_v[h]; jh = (jh >= 0 && jh < CAP_V) ? jh : 0;
            int jt = id_v[t]; jt = (jt >= 0 && jt < CAP_V) ? jt : 0;
            float2 xh = make_float2(0.f, 0.f), xt = make_float2(0.f, 0.f);
            {
                int d = deg_v[jh], mm = min(d, ST_ETT);
                for (int k = 0; k < mm; ++k) {
                    unsigned si = (unsigned)b_ett[jh * ST_ETT + k];
                    if (si < CAP_TP) {
                        float2 v = ((const float2*)(tet_proj + (size_t)si * 128))[lane];
                        xh.x += v.x; xh.y += v.y;
                    }
                }
                float inv = (d > 0) ? 1.f / (float)d : 0.f;
                xh.x *= inv; xh.y *= inv;
            }
            {
                int d = deg_v[jt], mm = min(d, ST_ETT);
                for (int k = 0; k < mm; ++k) {
                    unsigned si = (unsigned)b_ett[jt * ST_ETT + k];
                    if (si < CAP_TP) {
                        float2 v = ((const float2*)(tet_proj + (size_t)si * 128))[lane];
                        xt.x += v.x; xt.y += v.y;
                    }
                }
                float inv = (d > 0) ? 1.f / (float)d : 0.f;
                xt.x *= inv; xt.y *= inv;
            }
            float sh = xh.x + xh.y, st = xt.x + xt.y;
#pragma unroll
            for (int o = 32; o >= 1; o >>= 1) { sh += __shfl_xor(sh, o, 64); st += __shfl_xor(st, o, 64); }
            float muh = sh * (1.f / 128.f), mut = st * (1.f / 128.f);
            float2 dh = make_float2(xh.x - muh, xh.y - muh);
            float2 dt = make_float2(xt.x - mut, xt.y - mut);
            float vh_ = dh.x * dh.x + dh.y * dh.y, vt_ = dt.x * dt.x + dt.y * dt.y;
#pragma unroll
            for (int o = 32; o >= 1; o >>= 1) { vh_ += __shfl_xor(vh_, o, 64); vt_ += __shfl_xor(vt_, o, 64); }
            float rsh = rsqrtf(vh_ * (1.f / 128.f) + 1e-5f);
            float rst = rsqrtf(vt_ * (1.f / 128.f) + 1e-5f);
            float2 lw = ((const float2*)lnw)[lane];
            float2 lb = ((const float2*)lnb)[lane];
            float2 lnh = make_float2(dh.x * rsh * lw.x + lb.x, dh.y * rsh * lw.y + lb.y);
            float2 lnt = make_float2(dt.x * rst * lw.x + lb.x, dt.y * rst * lw.y + lb.y);
            float2 eh = ((const float2*)emb)[(size_t)h * 64 + lane];
            float2 etv = ((const float2*)emb)[(size_t)t * 64 + lane];
            float2 rr = ((const float2*)rel)[(size_t)r * 64 + lane];
            float dx = (w0 * eh.x + w1 * lnh.x) + rr.x - (w0 * etv.x + w1 * lnt.x);
            float dy = (w0 * eh.y + w1 * lnh.y) + rr.y - (w0 * etv.y + w1 * lnt.y);
            float ss = dx * dx + dy * dy;
#pragma unroll
            for (int o = 32; o >= 1; o >>= 1) ss += __shfl_xor(ss, o, 64);
            if (lane == 0) out[b] = gamma[0] - sqrtf(ss);
        }
    }
}

// ---------------- host launcher ----------------

extern "C" void kernel_launch(void* const* d_in, const int* in_sizes, int n_in,
                              void* d_out, int out_size, void* d_ws, size_t ws_size,
                              hipStream_t stream) {
    const float* entity_emb = (const float*)d_in[0];
    const float* relation_emb = (const float*)d_in[1];
    const float* g2_w1 = (const float*)d_in[2];
    const float* g2_b1 = (const float*)d_in[3];
    const float* g2_w2 = (const float*)d_in[4];
    const float* g2_b2 = (const float*)d_in[5];
    const float* g3_w1 = (const float*)d_in[6];
    const float* g3_b1 = (const float*)d_in[7];
    const float* g3_w2 = (const float*)d_in[8];
    const float* g3_b2 = (const float*)d_in[9];
    const float* te_w = (const float*)d_in[10];
    const float* te_b = (const float*)d_in[11];
    const float* ln_w = (const float*)d_in[12];
    const float* ln_b = (const float*)d_in[13];
    const float* alpha = (const float*)d_in[14];
    const float* gamma = (const float*)d_in[15];
    const int* triples = (const int*)d_in[16];
    const int* et = (const int*)d_in[17];
    const int* tt = (const int*)d_in[18];
    const int* ett = (const int*)d_in[19];
    float* out = (float*)d_out;

    char* base = (char*)d_ws;
    size_t off = 0;
    auto take = [&](size_t bytes) -> void* {
        void* p = base + off;
        off = (off + bytes + 255) & ~(size_t)255;
        return p;
    };
    int* id_v = (int*)take((size_t)NE_ * 4);
    int* id_tp = (int*)take((size_t)NTET_ * 4);
    int* id_tri = (int*)take((size_t)NTRI_ * 4);
    int* ctr = (int*)take(64);
    int* deg_tri = (int*)take((size_t)CAP_TRI * 4);
    int* deg_tp = (int*)take((size_t)CAP_TP * 4);
    int* deg_v = (int*)take((size_t)CAP_V * 4);
    int* b_et = (int*)take((size_t)CAP_TRI * ST_ET * 4);
    int* b_tt = (int*)take((size_t)CAP_TP * ST_TT * 4);
    int* b_ett = (int*)take((size_t)CAP_V * ST_ETT * 4);
    unsigned short* wb = (unsigned short*)take((size_t)262144 * 2);
    unsigned short* tri_agg = (unsigned short*)take((size_t)CAP_TRI * D_ * 2);
    unsigned short* h_tri = (unsigned short*)take((size_t)CAP_TRI * TRIH_ * 2);
    unsigned short* tri_c = (unsigned short*)take((size_t)CAP_TRI * TRIH_ * 2);
    unsigned short* h_tet = (unsigned short*)take((size_t)CAP_TP * TETH_ * 2);
    unsigned short* y_tet = (unsigned short*)take((size_t)CAP_TP * TETH_ * 2);
    float* tet_proj = (float*)take((size_t)CAP_TP * D_ * 4);
    if (off > ws_size) return;  // workspace too small -> visible validation failure

    hipMemsetAsync(ctr, 0, 64, stream);  // counters + both spin-barrier words

    mega_front<<<NBLK_F, 256, 0, stream>>>(triples, et, tt, ett,
                                           g2_w1, g2_w2, g3_w1, g3_w2, te_w, wb,
                                           id_v, id_tp, id_tri, ctr,
                                           deg_tri, deg_tp, deg_v, b_et, b_tt, b_ett);
    k_gather_tri<<<2048, 256, 0, stream>>>(ctr, deg_tri, b_et, entity_emb, (unsigned*)tri_agg);
    mega_back<<<NBLK_B, 256, 0, stream>>>(ctr, wb, tri_agg, h_tri, tri_c,
                                          deg_tp, b_tt, h_tet, y_tet, tet_proj,
                                          deg_v, b_ett, id_v,
                                          g2_b1, g2_b2, g3_b1, g3_b2, te_b,
                                          entity_emb, relation_emb, ln_w, ln_b,
                                          alpha, gamma, triples, out, &ctr[9]);
}

// Round 16
// 125.321 us; speedup vs baseline: 6.1339x; 4.0480x over previous
//
#include <hip/hip_runtime.h>
#include <cmath>

#define NE_     200000
#define NR_     500
#define D_      128
#define TRIH_   256
#define TETH_   256
#define NTRI_   500000
#define NTET_   200000
#define B_      8192
#define EET_    1500000
#define ETT_    800000
#define EETT_   800000

// compact-row caps (validated r3-r11: actual c_tri~7.8k, c_tp~2k, c_v~500)
#define CAP_V   2048
#define CAP_TP  8192
#define CAP_TRI 12288

// strided bucket widths (avg degrees ~7.6 / ~4 / ~4; Poisson tails << these; guarded)
#define ST_ET   64
#define ST_TT   32
#define ST_ETT  32

#define COARSEN 8
#define CHUNK   (256 * COARSEN)

#define NBC_V   ((NE_   + CHUNK - 1) / CHUNK)   // 98
#define NBC_TP  ((NTET_ + CHUNK - 1) / CHUNK)   // 98
#define NBC_TRI ((NTRI_ + CHUNK - 1) / CHUNK)   // 245
#define NBF_ET  ((EET_  + CHUNK - 1) / CHUNK)   // 733
#define NBF_TT  ((ETT_  + CHUNK - 1) / CHUNK)   // 391
#define NBF_ETT ((EETT_ + CHUNK - 1) / CHUNK)   // 391
#define MARKB   1024

// wb (bf16 weights) offsets in ushorts
#define WB_G2W1 0
#define WB_G2W2 32768
#define WB_G3W1 98304
#define WB_G3W2 163840
#define WB_TE   229376

// ctr: [0]=c_v [1]=c_tp [2]=c_tri

typedef float f32x4 __attribute__((ext_vector_type(4)));
typedef short s16x8 __attribute__((ext_vector_type(8)));

__device__ __forceinline__ float gelu_exact(float v) {
    return 0.5f * v * (1.0f + erff(v * 0.70710678118654752f));
}

__device__ __forceinline__ unsigned short f2bf(float f) {
    unsigned int u = __float_as_uint(f);
    unsigned int r = (u + 0x7fffu + ((u >> 16) & 1u)) >> 16;
    return (unsigned short)r;
}

__device__ __forceinline__ float bf2f(unsigned int u) {
    return __uint_as_float(u << 16);
}

__device__ __forceinline__ int wave_rank_emit(bool pred, int* lcnt, int lane) {
    unsigned long long mask = __ballot(pred);
    int rank = __popcll(mask & ((1ull << lane) - 1ull));
    int total = __popcll(mask);
    int wb = 0;
    if (lane == 0 && total) wb = atomicAdd(lcnt, total);
    wb = __shfl(wb, 0, 64);
    return pred ? (wb + rank) : -1;
}

// ---------------- K1: init ids/ctr + weight cvt + zero deg ----------------

__global__ void k_init(int* __restrict__ id_v, int* __restrict__ id_tp,
                       int* __restrict__ id_tri, int* __restrict__ ctr,
                       const float* __restrict__ w1, const float* __restrict__ w2,
                       const float* __restrict__ w3, const float* __restrict__ w4,
                       const float* __restrict__ w5, unsigned short* __restrict__ wb,
                       int* __restrict__ deg_tri, int* __restrict__ deg_tp,
                       int* __restrict__ deg_v) {
    int i = blockIdx.x * blockDim.x + threadIdx.x;
    int st = gridDim.x * blockDim.x;
    for (int x = i; x < NE_; x += st) id_v[x] = -1;
    for (int x = i; x < NTET_; x += st) id_tp[x] = -1;
    for (int x = i; x < NTRI_; x += st) id_tri[x] = -1;
    if (i < 16) ctr[i] = 0;
    for (int x = i; x < 262144; x += st) {
        float f;
        if (x < 32768)       f = w1[x];
        else if (x < 98304)  f = w2[x - 32768];
        else if (x < 163840) f = w3[x - 98304];
        else if (x < 229376) f = w4[x - 163840];
        else                 f = w5[x - 229376];
        wb[x] = f2bf(f);
    }
    for (int x = i; x < CAP_TRI; x += st) deg_tri[x] = 0;
    for (int x = i; x < CAP_TP; x += st) deg_tp[x] = 0;
    for (int x = i; x < CAP_V; x += st) deg_v[x] = 0;
}

// ---------------- marks (plain stores) ----------------

__global__ void k_mark_v(const int* __restrict__ triples, int* __restrict__ id_v) {
    int b = blockIdx.x * blockDim.x + threadIdx.x;
    if (b >= B_) return;
    id_v[triples[b * 3 + 0]] = -2;
    id_v[triples[b * 3 + 2]] = -2;
}

__global__ void k_mark_tp(const int* __restrict__ ett, const int* __restrict__ id_v,
                          int* __restrict__ id_tp) {
    int i = blockIdx.x * blockDim.x + threadIdx.x;
    int st = gridDim.x * blockDim.x;
    for (int e = i; e < EETT_; e += st)
        if (id_v[ett[e]] != -1) id_tp[ett[EETT_ + e]] = -2;
}

// ---------------- block-aggregated compact (r5-validated) ----------------

__device__ void do_compact(int* __restrict__ arr, int n, int* __restrict__ g, int cap,
                           int bid, int* lcnt, int* lbase) {
    if (threadIdx.x == 0) *lcnt = 0;
    __syncthreads();
    const int lane = threadIdx.x & 63;
    const int base = bid * CHUNK;
    int pos[COARSEN];
#pragma unroll
    for (int u = 0; u < COARSEN; ++u) {
        int e = base + u * 256 + threadIdx.x;
        bool pred = (e < n) && (arr[e] == -2);
        pos[u] = wave_rank_emit(pred, lcnt, lane);
    }
    __syncthreads();
    if (threadIdx.x == 0) *lbase = *lcnt ? atomicAdd(g, *lcnt) : 0;
    __syncthreads();
    const int b0 = *lbase;
#pragma unroll
    for (int u = 0; u < COARSEN; ++u) {
        if (pos[u] >= 0) {
            int e = base + u * 256 + threadIdx.x;
            int idx = b0 + pos[u];
            arr[e] = (idx < cap) ? idx : -1;
        }
    }
}

// ---------------- direct-bucket filter: bkt[dst*stride + slot] = src ----------------

__device__ void do_filter(const int* __restrict__ e0, const int* __restrict__ e1,
                          const int* __restrict__ map0, const int* __restrict__ map1,
                          int n, int* __restrict__ deg, int* __restrict__ bkt,
                          int stride, int bid) {
#pragma unroll
    for (int u = 0; u < COARSEN; ++u) {
        int e = bid * CHUNK + u * 256 + threadIdx.x;
        if (e < n) {
            int m1 = map1[e1[e]];
            if (m1 >= 0) {
                int src = map0 ? map0[e0[e]] : e0[e];
                if (src >= 0) {
                    int slot = atomicAdd(&deg[m1], 1);
                    if (slot < stride) bkt[m1 * stride + slot] = src;
                }
            }
        }
    }
}

// K4: compact_v || compact_tp || mark_tri
__launch_bounds__(256)
__global__ void k_p4(const int* __restrict__ tt, int* __restrict__ id_v,
                     int* __restrict__ id_tp, int* __restrict__ id_tri,
                     int* __restrict__ ctr) {
    __shared__ int lcnt, lbase;
    int bid = blockIdx.x;
    if (bid < NBC_V) { do_compact(id_v, NE_, &ctr[0], CAP_V, bid, &lcnt, &lbase); return; }
    bid -= NBC_V;
    if (bid < NBC_TP) { do_compact(id_tp, NTET_, &ctr[1], CAP_TP, bid, &lcnt, &lbase); return; }
    bid -= NBC_TP;
    int i = bid * 256 + threadIdx.x;
    int st = MARKB * 256;
    for (int e = i; e < ETT_; e += st)
        if (id_tp[tt[ETT_ + e]] != -1) id_tri[tt[e]] = -2;
}

// K5: compact_tri || filter_ett (direct bucket into b_ett + deg_v)
__launch_bounds__(256)
__global__ void k_p5(int* __restrict__ id_tri, const int* __restrict__ ett,
                     const int* __restrict__ id_v, const int* __restrict__ id_tp,
                     int* __restrict__ deg_v, int* __restrict__ b_ett,
                     int* __restrict__ ctr) {
    __shared__ int lcnt, lbase;
    int bid = blockIdx.x;
    if (bid < NBC_TRI) { do_compact(id_tri, NTRI_, &ctr[2], CAP_TRI, bid, &lcnt, &lbase); return; }
    bid -= NBC_TRI;
    do_filter(ett + EETT_, ett, id_tp, id_v, EETT_, deg_v, b_ett, ST_ETT, bid);
}

// K6: filter_et || filter_tt (direct buckets)
__launch_bounds__(256)
__global__ void k_p6(const int* __restrict__ et, const int* __restrict__ tt,
                     const int* __restrict__ id_tri, const int* __restrict__ id_tp,
                     int* __restrict__ deg_tri, int* __restrict__ b_et,
                     int* __restrict__ deg_tp, int* __restrict__ b_tt) {
    int bid = blockIdx.x;
    if (bid < NBF_ET) {
        do_filter(et, et + EET_, nullptr, id_tri, EET_, deg_tri, b_et, ST_ET, bid);
        return;
    }
    bid -= NBF_ET;
    do_filter(tt, tt + ETT_, id_tri, id_tp, ETT_, deg_tp, b_tt, ST_TT, bid);
}

// ---------------- K7: gather-mean entity->triangle, writes bf16 means ----------------

__global__ void k_gather_tri(const int* __restrict__ ctr, const int* __restrict__ deg,
                             const int* __restrict__ bkt, const float* __restrict__ emb,
                             unsigned* __restrict__ outb /* [CAP_TRI][64] uints */) {
    const int c = min(ctr[2], CAP_TRI);
    const int lane = threadIdx.x & 63;
    int row = (blockIdx.x * blockDim.x + threadIdx.x) >> 6;
    const int nw = (gridDim.x * blockDim.x) >> 6;
    for (; row < c; row += nw) {
        int d = deg[row];
        int m = min(d, ST_ET);
        float ax = 0.f, ay = 0.f;
        for (int k = 0; k < m; ++k) {
            unsigned si = (unsigned)bkt[row * ST_ET + k];
            if (si < NE_) {
                float2 v = ((const float2*)(emb + (size_t)si * 128))[lane];
                ax += v.x; ay += v.y;
            }
        }
        float inv = (d > 0) ? 1.f / (float)d : 0.f;
        outb[(size_t)row * 64 + lane] =
            (unsigned)f2bf(ax * inv) | ((unsigned)f2bf(ay * inv) << 16);
    }
}

// ---------------- MFMA helper (validated r3-r11) ----------------

template<int KU>
__device__ __forceinline__ f32x4 tile_mma(const uint4* pa, int sa, const uint4* pb, int sb,
                                          int fo, f32x4 acc) {
#pragma unroll
    for (int kk = 0; kk < KU / 4; ++kk) {
        s16x8 a = *(const s16x8*)&pa[(kk * 4 + fo) ^ sa];
        s16x8 b = *(const s16x8*)&pb[(kk * 4 + fo) ^ sb];
        acc = __builtin_amdgcn_mfma_f32_16x16x32_bf16(a, b, acc, 0, 0, 0);
    }
    return acc;
}

// ---------------- GEMM: 32 rows x 64 cols/block (r10/r11-validated) ----------------

template<int K, int ACT, bool OBF>
__launch_bounds__(256)
__global__ void k_gemm(const int* __restrict__ ctrp, int ctr_idx, int cap,
                       const unsigned short* __restrict__ A,
                       const unsigned short* __restrict__ Wb, const float* __restrict__ bias,
                       void* __restrict__ Cv, int N) {
    constexpr int KU = K / 8;
    __shared__ uint4 xs[32 * KU];
    __shared__ uint4 ws[64 * KU];
    const int c = min(ctrp[ctr_idx], cap);
    const int row0 = blockIdx.x * 32;
    if (row0 >= c) return;
    const int tid = threadIdx.x;
    const int gc0 = blockIdx.y * 64;
#pragma unroll
    for (int it = 0; it < KU / 8; ++it) {
        int u = tid + it * 256;
        int r = u / KU, ku = u % KU;
        xs[r * KU + (ku ^ (r & 7))] = *(const uint4*)&A[(size_t)(row0 + r) * K + ku * 8];
    }
#pragma unroll
    for (int it = 0; it < KU / 4; ++it) {
        int u = tid + it * 256;
        int r = u / KU, ku = u % KU;
        ws[r * KU + (ku ^ (r & 7))] = *(const uint4*)&Wb[(size_t)(gc0 + r) * K + ku * 8];
    }
    __syncthreads();

    const int w = tid >> 6, l = tid & 63;
    const int wr = (w >> 1) * 16, wc0 = (w & 1) * 32;
    const int fr = l & 15, fo = l >> 4;
    const int ra = wr + fr, rb0 = wc0 + fr, rb1 = wc0 + 16 + fr;
    f32x4 z = {0.f, 0.f, 0.f, 0.f};
    f32x4 acc0 = tile_mma<KU>(xs + ra * KU, ra & 7, ws + rb0 * KU, rb0 & 7, fo, z);
    f32x4 acc1 = tile_mma<KU>(xs + ra * KU, ra & 7, ws + rb1 * KU, rb1 & 7, fo, z);
    const int col0 = gc0 + wc0 + fr, col1 = col0 + 16;
    const float bb0 = bias[col0], bb1 = bias[col1];
#pragma unroll
    for (int j = 0; j < 4; ++j) {
        int grow = row0 + wr + fo * 4 + j;
        if (grow < c) {
            float v0 = acc0[j] + bb0;
            float v1 = acc1[j] + bb1;
            if (ACT == 1) { v0 = gelu_exact(v0); v1 = gelu_exact(v1); }
            if (OBF) {
                ((unsigned short*)Cv)[(size_t)grow * N + col0] = f2bf(v0);
                ((unsigned short*)Cv)[(size_t)grow * N + col1] = f2bf(v1);
            } else {
                ((float*)Cv)[(size_t)grow * N + col0] = v0;
                ((float*)Cv)[(size_t)grow * N + col1] = v1;
            }
        }
    }
}

// ---------------- K10: fused gather_tt + tet L1 (64-col chunk, y=4) ----------------

__launch_bounds__(256)
__global__ void k_tet1(const int* __restrict__ ctrp, const int* __restrict__ deg,
                       const int* __restrict__ bkt, const unsigned short* __restrict__ tri_c,
                       const unsigned short* __restrict__ Wb, const float* __restrict__ bias,
                       unsigned short* __restrict__ h_tet) {
    constexpr int KU = 32;
    __shared__ uint4 xs[32 * KU];
    __shared__ uint4 ws[64 * KU];
    const int c = min(ctrp[1], CAP_TP);
    const int row0 = blockIdx.x * 32;
    if (row0 >= c) return;
    const int tid = threadIdx.x, lane = tid & 63, wv = tid >> 6;
    const int gc0 = blockIdx.y * 64;
    for (int rr = wv * 8; rr < wv * 8 + 8; ++rr) {
        int row = row0 + rr;
        float a0 = 0.f, a1 = 0.f, a2 = 0.f, a3 = 0.f;
        int d = 0;
        if (row < c) {
            d = deg[row];
            int m = min(d, ST_TT);
            for (int k = 0; k < m; ++k) {
                unsigned si = (unsigned)bkt[row * ST_TT + k];
                if (si < CAP_TRI) {
                    uint2 p = ((const uint2*)(tri_c + (size_t)si * 256))[lane];
                    a0 += bf2f(p.x & 0xffffu); a1 += bf2f(p.x >> 16);
                    a2 += bf2f(p.y & 0xffffu); a3 += bf2f(p.y >> 16);
                }
            }
        }
        float inv = (d > 0) ? 1.f / (float)d : 0.f;
        uint2 o;
        o.x = (unsigned)f2bf(a0 * inv) | ((unsigned)f2bf(a1 * inv) << 16);
        o.y = (unsigned)f2bf(a2 * inv) | ((unsigned)f2bf(a3 * inv) << 16);
        int col0 = lane * 4;
        int ku = col0 >> 3, off = col0 & 7;
        *(uint2*)((unsigned short*)&xs[rr * KU + (ku ^ (rr & 7))] + off) = o;
    }
#pragma unroll
    for (int it = 0; it < KU / 4; ++it) {
        int u = tid + it * 256;
        int r = u / KU, ku = u % KU;
        ws[r * KU + (ku ^ (r & 7))] = *(const uint4*)&Wb[(size_t)(gc0 + r) * 256 + ku * 8];
    }
    __syncthreads();
    const int w = tid >> 6;
    const int wr = (w >> 1) * 16, wc0 = (w & 1) * 32;
    const int fr = lane & 15, fo = lane >> 4;
    const int ra = wr + fr, rb0 = wc0 + fr, rb1 = wc0 + 16 + fr;
    f32x4 z = {0.f, 0.f, 0.f, 0.f};
    f32x4 acc0 = tile_mma<KU>(xs + ra * KU, ra & 7, ws + rb0 * KU, rb0 & 7, fo, z);
    f32x4 acc1 = tile_mma<KU>(xs + ra * KU, ra & 7, ws + rb1 * KU, rb1 & 7, fo, z);
    const int col0 = gc0 + wc0 + fr, col1 = col0 + 16;
    const float bb0 = bias[col0], bb1 = bias[col1];
#pragma unroll
    for (int j = 0; j < 4; ++j) {
        int grow = row0 + wr + fo * 4 + j;
        if (grow < c) {
            h_tet[(size_t)grow * 256 + col0] = f2bf(gelu_exact(acc0[j] + bb0));
            h_tet[(size_t)grow * 256 + col1] = f2bf(gelu_exact(acc1[j] + bb1));
        }
    }
}

// ---------------- K13: final (v-gather + mean + LN + fusion + TransE) ----------------

__global__ void k_final(const float* __restrict__ emb, const float* __restrict__ rel,
                        const float* __restrict__ tet_proj, const int* __restrict__ deg_v,
                        const int* __restrict__ b_ett, const int* __restrict__ id_v,
                        const float* __restrict__ lnw, const float* __restrict__ lnb,
                        const float* __restrict__ alpha, const float* __restrict__ gamma,
                        const int* __restrict__ triples, float* __restrict__ out) {
    const int lane = threadIdx.x & 63;
    const int b = blockIdx.x * 4 + (threadIdx.x >> 6);
    if (b >= B_) return;
    float a0 = alpha[0], a1 = alpha[1];
    float m = fmaxf(a0, a1);
    float e0 = expf(a0 - m), e1 = expf(a1 - m);
    float w0 = e0 / (e0 + e1), w1 = e1 / (e0 + e1);
    int h = triples[b * 3 + 0];
    int r = triples[b * 3 + 1];
    int t = triples[b * 3 + 2];
    int jh = id_v[h]; jh = (jh >= 0 && jh < CAP_V) ? jh : 0;
    int jt = id_v[t]; jt = (jt >= 0 && jt < CAP_V) ? jt : 0;

    float2 xh = make_float2(0.f, 0.f), xt = make_float2(0.f, 0.f);
    {
        int d = deg_v[jh], mm = min(d, ST_ETT);
        for (int k = 0; k < mm; ++k) {
            unsigned si = (unsigned)b_ett[jh * ST_ETT + k];
            if (si < CAP_TP) {
                float2 v = ((const float2*)(tet_proj + (size_t)si * 128))[lane];
                xh.x += v.x; xh.y += v.y;
            }
        }
        float inv = (d > 0) ? 1.f / (float)d : 0.f;
        xh.x *= inv; xh.y *= inv;
    }
    {
        int d = deg_v[jt], mm = min(d, ST_ETT);
        for (int k = 0; k < mm; ++k) {
            unsigned si = (unsigned)b_ett[jt * ST_ETT + k];
            if (si < CAP_TP) {
                float2 v = ((const float2*)(tet_proj + (size_t)si * 128))[lane];
                xt.x += v.x; xt.y += v.y;
            }
        }
        float inv = (d > 0) ? 1.f / (float)d : 0.f;
        xt.x *= inv; xt.y *= inv;
    }
    float sh = xh.x + xh.y, st = xt.x + xt.y;
#pragma unroll
    for (int o = 32; o >= 1; o >>= 1) { sh += __shfl_xor(sh, o, 64); st += __shfl_xor(st, o, 64); }
    float muh = sh * (1.f / 128.f), mut = st * (1.f / 128.f);
    float2 dh = make_float2(xh.x - muh, xh.y - muh);
    float2 dt = make_float2(xt.x - mut, xt.y - mut);
    float vh_ = dh.x * dh.x + dh.y * dh.y, vt_ = dt.x * dt.x + dt.y * dt.y;
#pragma unroll
    for (int o = 32; o >= 1; o >>= 1) { vh_ += __shfl_xor(vh_, o, 64); vt_ += __shfl_xor(vt_, o, 64); }
    float rsh = rsqrtf(vh_ * (1.f / 128.f) + 1e-5f);
    float rst = rsqrtf(vt_ * (1.f / 128.f) + 1e-5f);
    float2 lw = ((const float2*)lnw)[lane];
    float2 lb = ((const float2*)lnb)[lane];
    float2 lnh = make_float2(dh.x * rsh * lw.x + lb.x, dh.y * rsh * lw.y + lb.y);
    float2 lnt = make_float2(dt.x * rst * lw.x + lb.x, dt.y * rst * lw.y + lb.y);
    float2 eh = ((const float2*)emb)[(size_t)h * 64 + lane];
    float2 etv = ((const float2*)emb)[(size_t)t * 64 + lane];
    float2 rr = ((const float2*)rel)[(size_t)r * 64 + lane];
    float dx = (w0 * eh.x + w1 * lnh.x) + rr.x - (w0 * etv.x + w1 * lnt.x);
    float dy = (w0 * eh.y + w1 * lnh.y) + rr.y - (w0 * etv.y + w1 * lnt.y);
    float ss = dx * dx + dy * dy;
#pragma unroll
    for (int o = 32; o >= 1; o >>= 1) ss += __shfl_xor(ss, o, 64);
    if (lane == 0) out[b] = gamma[0] - sqrtf(ss);
}

// ---------------- host launcher ----------------

extern "C" void kernel_launch(void* const* d_in, const int* in_sizes, int n_in,
                              void* d_out, int out_size, void* d_ws, size_t ws_size,
                              hipStream_t stream) {
    const float* entity_emb = (const float*)d_in[0];
    const float* relation_emb = (const float*)d_in[1];
    const float* g2_w1 = (const float*)d_in[2];
    const float* g2_b1 = (const float*)d_in[3];
    const float* g2_w2 = (const float*)d_in[4];
    const float* g2_b2 = (const float*)d_in[5];
    const float* g3_w1 = (const float*)d_in[6];
    const float* g3_b1 = (const float*)d_in[7];
    const float* g3_w2 = (const float*)d_in[8];
    const float* g3_b2 = (const float*)d_in[9];
    const float* te_w = (const float*)d_in[10];
    const float* te_b = (const float*)d_in[11];
    const float* ln_w = (const float*)d_in[12];
    const float* ln_b = (const float*)d_in[13];
    const float* alpha = (const float*)d_in[14];
    const float* gamma = (const float*)d_in[15];
    const int* triples = (const int*)d_in[16];
    const int* et = (const int*)d_in[17];
    const int* tt = (const int*)d_in[18];
    const int* ett = (const int*)d_in[19];
    float* out = (float*)d_out;

    char* base = (char*)d_ws;
    size_t off = 0;
    auto take = [&](size_t bytes) -> void* {
        void* p = base + off;
        off = (off + bytes + 255) & ~(size_t)255;
        return p;
    };
    int* id_v = (int*)take((size_t)NE_ * 4);
    int* id_tp = (int*)take((size_t)NTET_ * 4);
    int* id_tri = (int*)take((size_t)NTRI_ * 4);
    int* ctr = (int*)take(64);
    int* deg_tri = (int*)take((size_t)CAP_TRI * 4);
    int* deg_tp = (int*)take((size_t)CAP_TP * 4);
    int* deg_v = (int*)take((size_t)CAP_V * 4);
    int* b_et = (int*)take((size_t)CAP_TRI * ST_ET * 4);
    int* b_tt = (int*)take((size_t)CAP_TP * ST_TT * 4);
    int* b_ett = (int*)take((size_t)CAP_V * ST_ETT * 4);
    unsigned short* wb = (unsigned short*)take((size_t)262144 * 2);
    unsigned short* tri_agg = (unsigned short*)take((size_t)CAP_TRI * D_ * 2);
    unsigned short* h_tri = (unsigned short*)take((size_t)CAP_TRI * TRIH_ * 2);
    unsigned short* tri_c = (unsigned short*)take((size_t)CAP_TRI * TRIH_ * 2);
    unsigned short* h_tet = (unsigned short*)take((size_t)CAP_TP * TETH_ * 2);
    unsigned short* y_tet = (unsigned short*)take((size_t)CAP_TP * TETH_ * 2);
    float* tet_proj = (float*)take((size_t)CAP_TP * D_ * 4);
    if (off > ws_size) return;  // workspace too small -> visible validation failure

    k_init<<<2048, 256, 0, stream>>>(id_v, id_tp, id_tri, ctr,
                                     g2_w1, g2_w2, g3_w1, g3_w2, te_w, wb,
                                     deg_tri, deg_tp, deg_v);
    k_mark_v<<<(B_ + 255) / 256, 256, 0, stream>>>(triples, id_v);
    k_mark_tp<<<MARKB, 256, 0, stream>>>(ett, id_v, id_tp);
    k_p4<<<NBC_V + NBC_TP + MARKB, 256, 0, stream>>>(tt, id_v, id_tp, id_tri, ctr);
    k_p5<<<NBC_TRI + NBF_ETT, 256, 0, stream>>>(id_tri, ett, id_v, id_tp, deg_v, b_ett, ctr);
    k_p6<<<NBF_ET + NBF_TT, 256, 0, stream>>>(et, tt, id_tri, id_tp,
                                              deg_tri, b_et, deg_tp, b_tt);
    k_gather_tri<<<2048, 256, 0, stream>>>(ctr, deg_tri, b_et, entity_emb, (unsigned*)tri_agg);

    dim3 gtri(CAP_TRI / 32, TRIH_ / 64);
    k_gemm<128, 1, true><<<gtri, 256, 0, stream>>>(ctr, 2, CAP_TRI, tri_agg,
                                                   wb + WB_G2W1, g2_b1, h_tri, TRIH_);
    k_gemm<256, 0, true><<<gtri, 256, 0, stream>>>(ctr, 2, CAP_TRI, h_tri,
                                                   wb + WB_G2W2, g2_b2, tri_c, TRIH_);
    dim3 gtet(CAP_TP / 32, TETH_ / 64);
    k_tet1<<<gtet, 256, 0, stream>>>(ctr, deg_tp, b_tt, tri_c, wb + WB_G3W1, g3_b1, h_tet);
    k_gemm<256, 0, true><<<gtet, 256, 0, stream>>>(ctr, 1, CAP_TP, h_tet,
                                                   wb + WB_G3W2, g3_b2, y_tet, TETH_);
    dim3 gproj(CAP_TP / 32, D_ / 64);
    k_gemm<256, 0, false><<<gproj, 256, 0, stream>>>(ctr, 1, CAP_TP, y_tet,
                                                     wb + WB_TE, te_b, tet_proj, D_);
    k_final<<<(B_ + 3) / 4, 256, 0, stream>>>(entity_emb, relation_emb, tet_proj,
                                              deg_v, b_ett, id_v, ln_w, ln_b,
                                              alpha, gamma, triples, out);
}